// Round 9
// baseline (1305.923 us; speedup 1.0000x reference)
//
#include <hip/hip_runtime.h>
#include <hip/hip_bf16.h>
#include <type_traits>

// LogVAE. R15 = R14 resubmit (container infra failed twice; no measurement).
//  lstm restructured 8->4 waves (256 thr, 1 wave/SIMD via launch_bounds(256,1)):
//  wave w owns hidden [32w,32w+32) = 2 N-tiles. Same per-SIMD MFMA/VALU work,
//  but: barrier collects 4 waves not 8; LDS A-frag reads halve; cell0 epilogue
//  overlaps ntile1 MFMAs within the wave (disjoint pipes, no lockstep twin).
//  K-split dropped (8 indep 4-deep chains = enough ILP); gx C-in + lane-rotated
//  reg-dt scheme kept from R12. ~320 VGPR (ok at 1 wave/SIMD, no spill <=450).
//  init/latent/out unchanged from R13.

#define B_ 256
#define S_ 1024
#define NF_ 32
#define E_ 64
#define H_ 128
#define L_ 64
#define C_ 31

#define ACTS_OFF 0
#define TS_OFF   8118528   // 256*1023*31
#define MU_OFF   8380416   // + 256*1023
#define LV_OFF   8396800   // + 256*64

#define LOG2E  1.44269504f
#define LOG2E2 2.88539008f

typedef __attribute__((ext_vector_type(8))) short short8;
typedef __attribute__((ext_vector_type(4))) float float4v;

__device__ inline unsigned short f2bf(float x){
  union { float f; unsigned u; } a; a.f = x;
  unsigned r = a.u + 0x7FFFu + ((a.u >> 16) & 1u);
  return (unsigned short)(r >> 16);
}
__device__ inline float frcp(float x){
#if __has_builtin(__builtin_amdgcn_rcpf)
  return __builtin_amdgcn_rcpf(x);
#else
  return 1.0f / x;
#endif
}
__device__ inline float fexp2(float x){
#if __has_builtin(__builtin_amdgcn_exp2f)
  return __builtin_amdgcn_exp2f(x);
#else
  return exp2f(x);
#endif
}
__device__ inline float fsig(float x){ return frcp(1.0f + fexp2(-LOG2E*x)); }
__device__ inline float leaky(float x){ return x >= 0.0f ? x : 0.01f*x; }
__device__ inline float wredsum(float v){
  v += __shfl_xor(v, 32, 64);
  v += __shfl_xor(v, 16, 64);
  v += __shfl_xor(v,  8, 64);
  v += __shfl_xor(v,  4, 64);
  v += __shfl_xor(v,  2, 64);
  v += __shfl_xor(v,  1, 64);
  return v;
}

// ---------------- Kernel A: x_emb = LN(leaky(x @ W.T + b)) -> bf16 [S][B][E] --
// 4 waves/block, 16 rows/wave. Per wave: W row (lane's output) cached in
// VGPRs once; per row: x loaded via SGPRs (wave-uniform), 32 v_fmac(s,v).
#define INIT_ROWS 16
__global__ __launch_bounds__(256) void init_kernel(
    const float* __restrict__ x, const float* __restrict__ W,
    const float* __restrict__ bias, const float* __restrict__ gam,
    const float* __restrict__ beta, unsigned short* __restrict__ xemb)
{
  if (blockIdx.x == 0 && threadIdx.x < 64)
    xemb[(size_t)S_*B_*E_ + threadIdx.x] = 0;

  const int wave = threadIdx.x >> 6, lane = threadIdx.x & 63;
  float wf[NF_];
  {
    const float4* wr = (const float4*)(W + lane * NF_);
    #pragma unroll
    for (int j = 0; j < NF_/4; ++j){
      float4 t = wr[j];
      wf[4*j+0] = t.x; wf[4*j+1] = t.y; wf[4*j+2] = t.z; wf[4*j+3] = t.w;
    }
  }
  const float bb = bias[lane], gg = gam[lane], be = beta[lane];

  const int r0 = (blockIdx.x * 4 + wave) * INIT_ROWS;
  for (int rr = 0; rr < INIT_ROWS; ++rr){
    const int ru = __builtin_amdgcn_readfirstlane(r0 + rr);  // wave-uniform row
    const int b = ru >> 10, s = ru & 1023;
    const float* xr = x + (size_t)ru * NF_;   // SGPR-based -> s_loads
    float acc = bb;
    #pragma unroll
    for (int k = 0; k < NF_; ++k)
      acc = fmaf(xr[k], wf[k], acc);
    acc = leaky(acc);
    float m = wredsum(acc) * (1.0f/64.0f);
    float d = acc - m;
    float v = wredsum(d*d) * (1.0f/64.0f);
    float y = d * rsqrtf(v + 1e-5f) * gg + be;
    xemb[((size_t)s * B_ + b) * E_ + lane] = f2bf(y);   // [S][B][E]
  }
}

// ---------------- Kernel B: LSTM recurrence (4 waves, 2 N-tiles/wave) --------
// grid=64 (4 batch/WG), block=256 (4 waves). Wave w owns i,f,g,o gates of
// hidden [32w,32w+32) as 2 N-tiles (hu0 = 32w+c16, hu1 = hu0+16).
// At step dt (t mod 4), h A-rows = {dt,4+dt,8+dt,12+dt} (batch b at row 4b+dt,
// supplied by lanes c16&3==dt) -> h-product lands at reg dt = same slot as
// time-batched gx (A rows 4b+dt) and the gate read.
__global__ __launch_bounds__(256, 1) void lstm_kernel(
    const float* __restrict__ Wih,   // [512][64]
    const float* __restrict__ Whh,   // [512][128]
    const float* __restrict__ bih, const float* __restrict__ bhh,
    const unsigned short* __restrict__ xemb,  // [S][256][64] bf16 (+64 zero pad)
    int T,
    const float* __restrict__ h0, const float* __restrict__ c0, // null => ones/zeros
    float* __restrict__ hT_out,               // [256][128] fp32 or null
    unsigned short* __restrict__ hs_out)      // [T][256][128] bf16 or null
{
  __shared__ unsigned short hbuf[2][16*136];  // +8 pad/row
  const int tid = threadIdx.x;
  const int wave = tid >> 6, lane = tid & 63;
  const int q = lane >> 4, c16 = lane & 15;
  const int bt0 = blockIdx.x * 4;
  const int hu0 = wave * 32 + c16;            // ntile0 col; ntile1 = hu0+16

  // Persistent B frags: kb 0..3 = Whh (K=0..128), kb 4..5 = Wih (K=128..192)
  short8 Bf[2][4][6];
  float bias[2][4];
  #pragma unroll
  for (int nt = 0; nt < 2; ++nt){
    #pragma unroll
    for (int g = 0; g < 4; ++g){
      const int gcol = g*128 + hu0 + nt*16;
      bias[nt][g] = bih[gcol] + bhh[gcol];
      #pragma unroll
      for (int kb = 0; kb < 6; ++kb){
        union { short8 v; unsigned short u[8]; } tmp;
        #pragma unroll
        for (int j = 0; j < 8; ++j){
          int k = kb*32 + q*8 + j;
          float wv = (kb < 4) ? Whh[gcol*H_ + k] : Wih[gcol*E_ + (k - H_)];
          tmp.u[j] = f2bf(wv);
        }
        Bf[nt][g][kb] = tmp.v;
      }
    }
  }

  // LDS: zero both buffers, then fill storage rows {0,4,8,12} of buf0 with h0.
  unsigned short* hflat = &hbuf[0][0];
  for (int idx = tid; idx < 2*16*136; idx += 256) hflat[idx] = 0;
  __syncthreads();
  for (int e = tid; e < 512; e += 256){
    int b = e >> 7, k = e & 127;
    hbuf[0][(4*b)*136 + k] = h0 ? f2bf(h0[((size_t)(bt0 + b))*H_ + k])
                                : (unsigned short)0x3F80; // bf16(1.0)
  }
  float cst0 = c0 ? c0[((size_t)(bt0 + q))*H_ + hu0]      : 0.0f;
  float cst1 = c0 ? c0[((size_t)(bt0 + q))*H_ + hu0 + 16] : 0.0f;
  __syncthreads();

  // x window loads: ALL 64 lanes real. Lane A-row = c16 = 4*b_local + dt.
  const int xb = c16 >> 2, xdt = c16 & 3;
  const unsigned short* xbase = xemb + ((size_t)(bt0 + xb))*E_ + q*8;
  const size_t xrow = (size_t)B_*E_;
  auto xwin = [&](int wt)->const unsigned short*{
    int tt = wt + xdt; if (tt > T-1) tt = T-1;   // clamp: garbage rows unused
    return xbase + (size_t)tt * xrow;
  };

  // Prologue: gxA = gx(0..3); nx = x(4..7) in flight.
  float4v gxA[2][4], gxB[2][4];
  short8 nx0, nx1;
  { const unsigned short* p = xwin(0);
    nx0 = *(const short8*)p; nx1 = *(const short8*)(p + 32); }
  #pragma unroll
  for (int nt = 0; nt < 2; ++nt)
  #pragma unroll
  for (int g = 0; g < 4; ++g){
    float4v t = (float4v){bias[nt][g], bias[nt][g], bias[nt][g], bias[nt][g]};
    t = __builtin_amdgcn_mfma_f32_16x16x32_bf16(nx0, Bf[nt][g][4], t, 0, 0, 0);
    gxA[nt][g] = __builtin_amdgcn_mfma_f32_16x16x32_bf16(nx1, Bf[nt][g][5], t, 0, 0, 0);
  }
  { const unsigned short* p = xwin(4);
    nx0 = *(const short8*)p; nx1 = *(const short8*)(p + 32); }

  short8 Af0 = 0, Af1 = 0, Af2 = 0, Af3 = 0;   // zeros until a lane's first load

  // h A-frag read base: batch (c16>>2) stored at LDS row 4*(c16>>2) = c16&~3.
  // Same address for every dt — only the loading-lane predicate rotates.
  const unsigned short* haR0 = hflat + (c16 & ~3)*136 + q*8;  // buf0
  const unsigned short* haR1 = haR0 + 2176;                   // buf1
  unsigned short* hw0 = hflat + (4*q)*136 + hu0;              // write buf0 (+16 for nt1)
  unsigned short* hw1 = hw0 + 2176;                           // write buf1
  unsigned short* hsp = hs_out ? (hs_out + ((size_t)(bt0 + q))*H_ + hu0) : nullptr;

  // LSTM cell epilogue. Shared-rcp pairs:
  // sig(i)*tanh(g) = e^i(e^2g-1) / [(1+e^i)(1+e^2g)], same for o/c.
  auto cell = [&](float gi, float gf, float gg, float go, float& cs)->float{
    float ei  = fexp2(gi * LOG2E);
    float e2g = fexp2(gg * LOG2E2);
    float t1  = (ei * (e2g - 1.0f)) * frcp((1.0f + ei) * (1.0f + e2g));
    float sf  = fsig(gf);
    float c   = fmaf(sf, cs, t1);
    cs = c;
    float eo  = fexp2(go * LOG2E);
    float e2c = fexp2(fminf(c * LOG2E2, 126.0f));   // clamp: c can accumulate
    return (eo * (e2c - 1.0f)) * frcp((1.0f + eo) * (1.0f + e2c));
  };

  // DT compile-time (integral_constant) -> acc subscripts fold (rule #20).
  // pre(): independent work in the ds_read latency window (BEFORE MFMAs).
  // post(): runs AFTER the main clusters consumed their C-in (gx rotation).
  auto step = [&](int t, auto dtc, auto&& pre, auto&& post){
    constexpr int dt = decltype(dtc)::value;
    const unsigned short* ha = (t & 1) ? haR1 : haR0;
    if ((c16 & 3) == dt){            // this step's h-supplier lanes
      Af0 = *(const short8*)(ha);
      Af1 = *(const short8*)(ha + 32);
      Af2 = *(const short8*)(ha + 64);
      Af3 = *(const short8*)(ha + 96);
    }
    pre();

    // ntile0 cluster then ntile1 cluster (4 indep 4-deep chains each).
    // cell0's epilogue VALU/trans can overlap ntile1's MFMAs (disjoint pipes).
    float4v a[2][4];
    #pragma unroll
    for (int nt = 0; nt < 2; ++nt){
      #pragma unroll
      for (int g = 0; g < 4; ++g)
        a[nt][g] = __builtin_amdgcn_mfma_f32_16x16x32_bf16(Af0, Bf[nt][g][0], gxA[nt][g], 0, 0, 0);
      #pragma unroll
      for (int g = 0; g < 4; ++g)
        a[nt][g] = __builtin_amdgcn_mfma_f32_16x16x32_bf16(Af1, Bf[nt][g][1], a[nt][g], 0, 0, 0);
      #pragma unroll
      for (int g = 0; g < 4; ++g)
        a[nt][g] = __builtin_amdgcn_mfma_f32_16x16x32_bf16(Af2, Bf[nt][g][2], a[nt][g], 0, 0, 0);
      #pragma unroll
      for (int g = 0; g < 4; ++g)
        a[nt][g] = __builtin_amdgcn_mfma_f32_16x16x32_bf16(Af3, Bf[nt][g][3], a[nt][g], 0, 0, 0);
    }

    post();   // safe: C-in (gxA) consumed by the clusters above

    float h0v = cell(a[0][0][dt], a[0][1][dt], a[0][2][dt], a[0][3][dt], cst0);
    float h1v = cell(a[1][0][dt], a[1][1][dt], a[1][2][dt], a[1][3][dt], cst1);
    unsigned vv;
    asm("v_cvt_pk_bf16_f32 %0, %1, %2" : "=v"(vv) : "v"(h0v), "v"(h1v));
    unsigned short lo = (unsigned short)(vv & 0xFFFFu);
    unsigned short hi = (unsigned short)(vv >> 16);
    unsigned short* hw = (t & 1) ? hw0 : hw1;       // write buf (1-cur)
    hw[0]  = lo;
    hw[16] = hi;
    if (hs_out){ hsp[0] = lo; hsp[16] = hi; hsp += (size_t)B_*H_; }
    if (hT_out && t == T-1){
      hT_out[((size_t)(bt0 + q))*H_ + hu0]      = h0v;
      hT_out[((size_t)(bt0 + q))*H_ + hu0 + 16] = h1v;
    }
    // Raw barrier: drain LDS only; globals stay in flight (R7).
    __builtin_amdgcn_sched_barrier(0);
    asm volatile("s_waitcnt lgkmcnt(0)" ::: "memory");
    __builtin_amdgcn_s_barrier();
    __builtin_amdgcn_sched_barrier(0);
  };

  using I0 = std::integral_constant<int,0>;
  using I1 = std::integral_constant<int,1>;
  using I2 = std::integral_constant<int,2>;
  using I3 = std::integral_constant<int,3>;
  auto nop = []{};

  const int nwin = T >> 2, ntail = T & 3;
  for (int w = 0; w < nwin; ++w){
    const int t0 = w << 2;
    step(t0+0, I0{}, [&]{
      // gxB = gx(t0+4 .. t0+7); consumes nx loaded 3 steps ago.
      #pragma unroll
      for (int nt = 0; nt < 2; ++nt)
      #pragma unroll
      for (int g = 0; g < 4; ++g){
        float4v tt = (float4v){bias[nt][g], bias[nt][g], bias[nt][g], bias[nt][g]};
        tt = __builtin_amdgcn_mfma_f32_16x16x32_bf16(nx0, Bf[nt][g][4], tt, 0, 0, 0);
        gxB[nt][g] = __builtin_amdgcn_mfma_f32_16x16x32_bf16(nx1, Bf[nt][g][5], tt, 0, 0, 0);
      }
    }, nop);
    step(t0+1, I1{}, [&]{
      // issue loads for window w+2; consumed 3 steps later (dt=0 of w+1).
      const unsigned short* p = xwin(t0 + 8);
      nx0 = *(const short8*)p; nx1 = *(const short8*)(p + 32);
    }, nop);
    step(t0+2, I2{}, nop, nop);
    step(t0+3, I3{}, nop, [&]{
      // window rotation AFTER the clusters consumed gxA as C-in
      #pragma unroll
      for (int nt = 0; nt < 2; ++nt)
      #pragma unroll
      for (int g = 0; g < 4; ++g) gxA[nt][g] = gxB[nt][g];
    });
  }
  // Tail (decoder T=1023: 3 steps). gxA already holds gx(nwin*4 ..).
  if (ntail > 0) step(nwin*4+0, I0{}, nop, nop);
  if (ntail > 1) step(nwin*4+1, I1{}, nop, nop);
  if (ntail > 2) step(nwin*4+2, I2{}, nop, nop);
}

// ---------------- Kernel C: mu/logvar/latent/dh0/dc0 ------------------------
__global__ __launch_bounds__(128) void latent_kernel(
    const float* __restrict__ hT, const float* __restrict__ eps,
    const float* __restrict__ mu_W, const float* __restrict__ mu_b,
    const float* __restrict__ mu_g, const float* __restrict__ mu_be,
    const float* __restrict__ lv_W, const float* __restrict__ lv_b,
    const float* __restrict__ lv_g, const float* __restrict__ lv_be,
    const float* __restrict__ lh_W, const float* __restrict__ lh_b,
    const float* __restrict__ lh_g, const float* __restrict__ lh_be,
    const float* __restrict__ lc_W, const float* __restrict__ lc_b,
    const float* __restrict__ lc_g, const float* __restrict__ lc_be,
    float* __restrict__ out, float* __restrict__ dh0, float* __restrict__ dc0)
{
  const int b = blockIdx.x, tid = threadIdx.x;
  const int wave = tid >> 6, lane = tid & 63;
  __shared__ float shT[H_];
  __shared__ float smu[L_], slv[L_], slat[L_];
  __shared__ float part[2];
  shT[tid] = hT[(size_t)b*H_ + tid];
  __syncthreads();
  {
    const float* W = wave ? lv_W : mu_W;
    float a = (wave ? lv_b : mu_b)[lane];
    for (int k = 0; k < H_; ++k) a += shT[k] * W[lane*H_ + k];
    a = leaky(a);
    float m = wredsum(a) * (1.0f/L_);
    float d = a - m;
    float v = wredsum(d*d) * (1.0f/L_);
    float y = d * rsqrtf(v + 1e-5f) * (wave ? lv_g : mu_g)[lane] + (wave ? lv_be : mu_be)[lane];
    out[(wave ? LV_OFF : MU_OFF) + (size_t)b*L_ + lane] = y;
    if (wave) slv[lane] = y; else smu[lane] = y;
  }
  __syncthreads();
  if (tid < L_) slat[tid] = smu[tid] + eps[(size_t)b*L_ + tid] * expf(0.5f*slv[tid]);
  __syncthreads();
  #pragma unroll 1
  for (int which = 0; which < 2; ++which){
    const float* W = which ? lc_W : lh_W;
    float p = (which ? lc_b : lh_b)[tid];
    for (int k = 0; k < L_; ++k) p += slat[k] * W[tid*L_ + k];
    p = leaky(p);
    float s = wredsum(p);
    if (lane == 0) part[wave] = s;
    __syncthreads();
    float mean = (part[0] + part[1]) * (1.0f/H_);
    __syncthreads();
    float d = p - mean;
    float s2 = wredsum(d*d);
    if (lane == 0) part[wave] = s2;
    __syncthreads();
    float var = (part[0] + part[1]) * (1.0f/H_);
    __syncthreads();
    float y = d * rsqrtf(var + 1e-5f) * (which ? lc_g : lh_g)[tid] + (which ? lc_be : lh_be)[tid];
    (which ? dc0 : dh0)[(size_t)b*H_ + tid] = y;
  }
}

// ---------------- Kernel D: acts/ts heads via MFMA (N=32: 31 acts + ts) -----
__global__ __launch_bounds__(256) void out_kernel(
    const unsigned short* __restrict__ hs,   // [1023][256][128] bf16
    const float* __restrict__ actW, const float* __restrict__ actB,
    const float* __restrict__ timeW, const float* __restrict__ timeB,
    float* __restrict__ out)
{
  const int wave = threadIdx.x >> 6, lane = threadIdx.x & 63;
  const int quad = lane >> 4, c16 = lane & 15;
  const int mt = blockIdx.x * 4 + wave;      // M-tile of 16 rows (r = t*256 + b)
  short8 Wf[2][4]; float biasn[2];
  #pragma unroll
  for (int ti = 0; ti < 2; ++ti){
    const int n = ti*16 + c16;
    biasn[ti] = (n < C_) ? actB[n] : timeB[0];
    #pragma unroll
    for (int kb = 0; kb < 4; ++kb){
      union { short8 v; unsigned short u[8]; } tmp;
      #pragma unroll
      for (int j = 0; j < 8; ++j){
        int k = kb*32 + quad*8 + j;
        tmp.u[j] = f2bf((n < C_) ? actW[n*H_ + k] : timeW[k]);
      }
      Wf[ti][kb] = tmp.v;
    }
  }
  const unsigned short* hp = hs + ((size_t)mt*16 + c16)*H_ + quad*8;
  float4v acc[2];
  #pragma unroll
  for (int ti = 0; ti < 2; ++ti) acc[ti] = (float4v){biasn[ti], biasn[ti], biasn[ti], biasn[ti]};
  #pragma unroll
  for (int kb = 0; kb < 4; ++kb){
    short8 a = *(const short8*)(hp + kb*32);
    acc[0] = __builtin_amdgcn_mfma_f32_16x16x32_bf16(a, Wf[0][kb], acc[0], 0, 0, 0);
    acc[1] = __builtin_amdgcn_mfma_f32_16x16x32_bf16(a, Wf[1][kb], acc[1], 0, 0, 0);
  }
  #pragma unroll
  for (int ti = 0; ti < 2; ++ti){
    const int n = ti*16 + c16;
    #pragma unroll
    for (int r = 0; r < 4; ++r){
      int rr = mt*16 + quad*4 + r;
      int tt = rr >> 8, b = rr & 255;
      float v = acc[ti][r];
      if (n < C_) out[ACTS_OFF + ((size_t)b*1023 + tt)*C_ + n] = v;
      else        out[TS_OFF + (size_t)b*1023 + tt] = v;
    }
  }
}

// ---------------- launch ----------------------------------------------------
extern "C" void kernel_launch(void* const* d_in, const int* in_sizes, int n_in,
                              void* d_out, int out_size, void* d_ws, size_t ws_size,
                              hipStream_t stream)
{
  (void)in_sizes; (void)n_in; (void)out_size; (void)ws_size;
  const float* x       = (const float*)d_in[0];
  const float* eps     = (const float*)d_in[1];
  const float* init_W  = (const float*)d_in[2];
  const float* init_b  = (const float*)d_in[3];
  const float* init_g  = (const float*)d_in[4];
  const float* init_be = (const float*)d_in[5];
  const float* enc_Wih = (const float*)d_in[6];
  const float* enc_Whh = (const float*)d_in[7];
  const float* enc_bih = (const float*)d_in[8];
  const float* enc_bhh = (const float*)d_in[9];
  const float* mu_W  = (const float*)d_in[10];
  const float* mu_b  = (const float*)d_in[11];
  const float* mu_g  = (const float*)d_in[12];
  const float* mu_be = (const float*)d_in[13];
  const float* lv_W  = (const float*)d_in[14];
  const float* lv_b  = (const float*)d_in[15];
  const float* lv_g  = (const float*)d_in[16];
  const float* lv_be = (const float*)d_in[17];
  const float* dec_Wih = (const float*)d_in[18];
  const float* dec_Whh = (const float*)d_in[19];
  const float* dec_bih = (const float*)d_in[20];
  const float* dec_bhh = (const float*)d_in[21];
  const float* lh_W  = (const float*)d_in[22];
  const float* lh_b  = (const float*)d_in[23];
  const float* lh_g  = (const float*)d_in[24];
  const float* lh_be = (const float*)d_in[25];
  const float* lc_W  = (const float*)d_in[26];
  const float* lc_b  = (const float*)d_in[27];
  const float* lc_g  = (const float*)d_in[28];
  const float* lc_be = (const float*)d_in[29];
  const float* act_W  = (const float*)d_in[30];
  const float* act_b  = (const float*)d_in[31];
  const float* time_W = (const float*)d_in[32];
  const float* time_b = (const float*)d_in[33];
  float* out = (float*)d_out;

  // workspace: xemb [1024][256][64] bf16 + 64-short zero pad, hs, hT, dh0, dc0
  unsigned short* xemb = (unsigned short*)d_ws;
  unsigned short* hs   = xemb + (size_t)S_*B_*E_ + 64;       // after pad
  float* hT  = (float*)(hs + (size_t)(S_-1)*B_*H_);
  float* dh0 = hT  + B_*H_;
  float* dc0 = dh0 + B_*H_;

  init_kernel<<<dim3((B_*S_)/(4*INIT_ROWS)), dim3(256), 0, stream>>>(
      x, init_W, init_b, init_g, init_be, xemb);

  lstm_kernel<<<dim3(64), dim3(256), 0, stream>>>(
      enc_Wih, enc_Whh, enc_bih, enc_bhh, xemb, S_,
      nullptr, nullptr, hT, nullptr);

  latent_kernel<<<dim3(B_), dim3(128), 0, stream>>>(
      hT, eps, mu_W, mu_b, mu_g, mu_be, lv_W, lv_b, lv_g, lv_be,
      lh_W, lh_b, lh_g, lh_be, lc_W, lc_b, lc_g, lc_be, out, dh0, dc0);

  lstm_kernel<<<dim3(64), dim3(256), 0, stream>>>(
      dec_Wih, dec_Whh, dec_bih, dec_bhh, xemb, S_-1,
      dh0, dc0, nullptr, hs);

  out_kernel<<<dim3((B_*(S_-1))/16/4), dim3(256), 0, stream>>>(
      hs, act_W, act_b, time_W, time_b, out);
}

// Round 10
// 1219.831 us; speedup vs baseline: 1.0706x; 1.0706x over previous
//
#include <hip/hip_runtime.h>
#include <hip/hip_bf16.h>
#include <type_traits>

// LogVAE. R16 (post-mortem R15: 4-wave/1-per-SIMD REGRESSED 491->565us —
//  2 waves/SIMD were covering each other's latency, not contending. 8-wave
//  R13 structure is right; revert lstm core to R13 byte-for-byte.)
//  NEW: output heads (acts/ts) fused into the decoder. h(t) lives in LDS at
//  each step's end; waves 0/1 compute the 2 N-tiles of [4 batch x 32 out]
//  for step t-1 (4 MFMAs + 4 ds_reads + 1 store each) inside the per-step
//  stall slack R15 proved exists. Kills hs stores (67MB), out_kernel's
//  67MB read + launch. Fixed supplier scheme: lanes c16%4==0 read rows
//  {0,4,8,12} of the READ buffer (= h(t-1)); D reg0 = (batch q, col c16).

#define B_ 256
#define S_ 1024
#define NF_ 32
#define E_ 64
#define H_ 128
#define L_ 64
#define C_ 31

#define ACTS_OFF 0
#define TS_OFF   8118528   // 256*1023*31
#define MU_OFF   8380416   // + 256*1023
#define LV_OFF   8396800   // + 256*64

#define LOG2E  1.44269504f
#define LOG2E2 2.88539008f

typedef __attribute__((ext_vector_type(8))) short short8;
typedef __attribute__((ext_vector_type(4))) float float4v;

__device__ inline unsigned short f2bf(float x){
  union { float f; unsigned u; } a; a.f = x;
  unsigned r = a.u + 0x7FFFu + ((a.u >> 16) & 1u);
  return (unsigned short)(r >> 16);
}
__device__ inline float frcp(float x){
#if __has_builtin(__builtin_amdgcn_rcpf)
  return __builtin_amdgcn_rcpf(x);
#else
  return 1.0f / x;
#endif
}
__device__ inline float fexp2(float x){
#if __has_builtin(__builtin_amdgcn_exp2f)
  return __builtin_amdgcn_exp2f(x);
#else
  return exp2f(x);
#endif
}
__device__ inline float fsig(float x){ return frcp(1.0f + fexp2(-LOG2E*x)); }
__device__ inline float leaky(float x){ return x >= 0.0f ? x : 0.01f*x; }
__device__ inline float wredsum(float v){
  v += __shfl_xor(v, 32, 64);
  v += __shfl_xor(v, 16, 64);
  v += __shfl_xor(v,  8, 64);
  v += __shfl_xor(v,  4, 64);
  v += __shfl_xor(v,  2, 64);
  v += __shfl_xor(v,  1, 64);
  return v;
}

// ---------------- Kernel A: x_emb = LN(leaky(x @ W.T + b)) -> bf16 [S][B][E] --
#define INIT_ROWS 16
__global__ __launch_bounds__(256) void init_kernel(
    const float* __restrict__ x, const float* __restrict__ W,
    const float* __restrict__ bias, const float* __restrict__ gam,
    const float* __restrict__ beta, unsigned short* __restrict__ xemb)
{
  if (blockIdx.x == 0 && threadIdx.x < 64)
    xemb[(size_t)S_*B_*E_ + threadIdx.x] = 0;

  const int wave = threadIdx.x >> 6, lane = threadIdx.x & 63;
  float wf[NF_];
  {
    const float4* wr = (const float4*)(W + lane * NF_);
    #pragma unroll
    for (int j = 0; j < NF_/4; ++j){
      float4 t = wr[j];
      wf[4*j+0] = t.x; wf[4*j+1] = t.y; wf[4*j+2] = t.z; wf[4*j+3] = t.w;
    }
  }
  const float bb = bias[lane], gg = gam[lane], be = beta[lane];

  const int r0 = (blockIdx.x * 4 + wave) * INIT_ROWS;
  for (int rr = 0; rr < INIT_ROWS; ++rr){
    const int ru = __builtin_amdgcn_readfirstlane(r0 + rr);  // wave-uniform row
    const int b = ru >> 10, s = ru & 1023;
    const float* xr = x + (size_t)ru * NF_;   // SGPR-based -> s_loads
    float acc = bb;
    #pragma unroll
    for (int k = 0; k < NF_; ++k)
      acc = fmaf(xr[k], wf[k], acc);
    acc = leaky(acc);
    float m = wredsum(acc) * (1.0f/64.0f);
    float d = acc - m;
    float v = wredsum(d*d) * (1.0f/64.0f);
    float y = d * rsqrtf(v + 1e-5f) * gg + be;
    xemb[((size_t)s * B_ + b) * E_ + lane] = f2bf(y);   // [S][B][E]
  }
}

// ---------------- Kernel B: LSTM recurrence (R13 core + fused out heads) -----
// grid=64 (4 batch/WG), block=512 (8 waves). Wave w owns i,f,g,o gates of
// hidden [16w,16w+16). At step dt (t mod 4), h A-rows = {dt,4+dt,8+dt,12+dt}
// (batch b at row 4b+dt, supplied by lanes c16&3==dt) -> h-product lands at
// reg dt = same slot as time-batched gx (A rows 4b+dt) and the gate read.
// Decoder (outp != null): waves 0/1 additionally compute out(t-1) per step.
__global__ __launch_bounds__(512, 2) void lstm_kernel(
    const float* __restrict__ Wih,   // [512][64]
    const float* __restrict__ Whh,   // [512][128]
    const float* __restrict__ bih, const float* __restrict__ bhh,
    const unsigned short* __restrict__ xemb,  // [S][256][64] bf16 (+64 zero pad)
    int T,
    const float* __restrict__ h0, const float* __restrict__ c0, // null => ones/zeros
    float* __restrict__ hT_out,               // [256][128] fp32 or null
    float* __restrict__ outp,                 // fused acts/ts output or null
    const float* __restrict__ actW, const float* __restrict__ actB,
    const float* __restrict__ timeW, const float* __restrict__ timeB)
{
  __shared__ unsigned short hbuf[2][16*136];  // +8 pad/row
  const int tid = threadIdx.x;
  const int wave = tid >> 6, lane = tid & 63;
  const int q = lane >> 4, c16 = lane & 15;
  const int bt0 = blockIdx.x * 4;
  const int hu = wave * 16 + c16;

  // Persistent B frags: kb 0..3 = Whh (K=0..128), kb 4..5 = Wih (K=128..192)
  short8 Bf[4][6];
  float bias[4];
  #pragma unroll
  for (int g = 0; g < 4; ++g){
    const int gcol = g*128 + hu;
    bias[g] = bih[gcol] + bhh[gcol];
    #pragma unroll
    for (int kb = 0; kb < 6; ++kb){
      union { short8 v; unsigned short u[8]; } tmp;
      #pragma unroll
      for (int j = 0; j < 8; ++j){
        int k = kb*32 + q*8 + j;
        float wv = (kb < 4) ? Whh[gcol*H_ + k] : Wih[gcol*E_ + (k - H_)];
        tmp.u[j] = f2bf(wv);
      }
      Bf[g][kb] = tmp.v;
    }
  }

  // Fused out-head B frags (decoder only, waves 0/1): n = wave*16 + c16.
  const bool do_out = (outp != nullptr) && (wave < 2);
  short8 Of0 = 0, Of1 = 0, Of2 = 0, Of3 = 0;
  float obias = 0.0f;
  if (do_out){
    const int n = wave*16 + c16;
    obias = (n < C_) ? actB[n] : timeB[0];
    union { short8 v; unsigned short u[8]; } tmp[4];
    #pragma unroll
    for (int kb = 0; kb < 4; ++kb)
      #pragma unroll
      for (int j = 0; j < 8; ++j){
        int k = kb*32 + q*8 + j;
        tmp[kb].u[j] = f2bf((n < C_) ? actW[n*H_ + k] : timeW[k]);
      }
    Of0 = tmp[0].v; Of1 = tmp[1].v; Of2 = tmp[2].v; Of3 = tmp[3].v;
  }

  // LDS: zero both buffers, then fill storage rows {0,4,8,12} of buf0 with h0.
  unsigned short* hflat = &hbuf[0][0];
  for (int idx = tid; idx < 2*16*136; idx += 512) hflat[idx] = 0;
  __syncthreads();
  {
    int b = tid >> 7, k = tid & 127;   // tid < 512 = 4*128
    hbuf[0][(4*b)*136 + k] = h0 ? f2bf(h0[((size_t)(bt0 + b))*H_ + k])
                                : (unsigned short)0x3F80; // bf16(1.0)
  }
  float cst = c0 ? c0[((size_t)(bt0 + q))*H_ + hu] : 0.0f;
  __syncthreads();

  // x window loads: ALL 64 lanes real. Lane A-row = c16 = 4*b_local + dt.
  const int xb = c16 >> 2, xdt = c16 & 3;
  const unsigned short* xbase = xemb + ((size_t)(bt0 + xb))*E_ + q*8;
  const size_t xrow = (size_t)B_*E_;
  auto xwin = [&](int wt)->const unsigned short*{
    int tt = wt + xdt; if (tt > T-1) tt = T-1;   // clamp: garbage rows unused
    return xbase + (size_t)tt * xrow;
  };

  // Prologue: gxA = gx(0..3); nx = x(4..7) in flight.
  float4v gxA[4], gxB[4];
  short8 nx0, nx1;
  { const unsigned short* p = xwin(0);
    nx0 = *(const short8*)p; nx1 = *(const short8*)(p + 32); }
  #pragma unroll
  for (int g = 0; g < 4; ++g){
    float4v t = (float4v){bias[g], bias[g], bias[g], bias[g]};
    t = __builtin_amdgcn_mfma_f32_16x16x32_bf16(nx0, Bf[g][4], t, 0, 0, 0);
    gxA[g] = __builtin_amdgcn_mfma_f32_16x16x32_bf16(nx1, Bf[g][5], t, 0, 0, 0);
  }
  { const unsigned short* p = xwin(4);
    nx0 = *(const short8*)p; nx1 = *(const short8*)(p + 32); }

  short8 Af0 = 0, Af1 = 0, Af2 = 0, Af3 = 0;   // zeros until a lane's first load
  short8 Po0 = 0, Po1 = 0, Po2 = 0, Po3 = 0;   // out-head h frags (waves 0/1)

  // h A-frag read base: batch (c16>>2) stored at LDS row 4*(c16>>2) = c16&~3.
  // Same address for every dt — only the loading-lane predicate rotates.
  const unsigned short* haR0 = hflat + (c16 & ~3)*136 + q*8;  // buf0
  const unsigned short* haR1 = haR0 + 2176;                   // buf1
  unsigned short* hw0 = hflat + (4*q)*136 + hu;               // write buf0
  unsigned short* hw1 = hw0 + 2176;                           // write buf1
  float zero_f = 0.0f;
  const float4v z4 = (float4v){0.0f, 0.0f, 0.0f, 0.0f};

  // Fused out-head for step tt_ = t-1: h(t-1) = READ buffer rows {0,4,8,12}.
  // Supplier lanes c16%4==0 read their own row c16; D reg0 = (batch q, col c16).
  auto out_head = [&](const unsigned short* ha, int tt_){
    if ((c16 & 3) == 0){
      Po0 = *(const short8*)(ha);
      Po1 = *(const short8*)(ha + 32);
      Po2 = *(const short8*)(ha + 64);
      Po3 = *(const short8*)(ha + 96);
    }
    float4v o = z4;
    o = __builtin_amdgcn_mfma_f32_16x16x32_bf16(Po0, Of0, o, 0, 0, 0);
    o = __builtin_amdgcn_mfma_f32_16x16x32_bf16(Po1, Of1, o, 0, 0, 0);
    o = __builtin_amdgcn_mfma_f32_16x16x32_bf16(Po2, Of2, o, 0, 0, 0);
    o = __builtin_amdgcn_mfma_f32_16x16x32_bf16(Po3, Of3, o, 0, 0, 0);
    const float val = o[0] + obias;
    const int n = wave*16 + c16;
    const size_t bq = (size_t)(bt0 + q);
    if (n < C_) outp[ACTS_OFF + (bq*(S_-1) + (size_t)tt_)*C_ + n] = val;
    else        outp[TS_OFF + bq*(S_-1) + (size_t)tt_] = val;
  };

  // DT compile-time (integral_constant) -> acc subscripts fold (rule #20).
  // pre(): independent work in the ds_read latency window (BEFORE MFMAs).
  // post(): runs AFTER the main cluster consumed its C-in (gx rotation).
  auto step = [&](int t, auto dtc, float4v (&gxP)[4], auto&& pre, auto&& post){
    constexpr int dt = decltype(dtc)::value;
    const unsigned short* ha = (t & 1) ? haR1 : haR0;
    if ((c16 & 3) == dt){            // this step's h-supplier lanes
      Af0 = *(const short8*)(ha);
      Af1 = *(const short8*)(ha + 32);
      Af2 = *(const short8*)(ha + 64);
      Af3 = *(const short8*)(ha + 96);
    }
    pre();
    // Fused out-head for t-1 (independent of recurrence chains; fills slack).
    if (do_out && t > 0) out_head(ha, t - 1);

    // K-split chains: aA = gx + kb0 + kb1 ; aB = kb2 + kb3 (from zero).
    // Fresh h rows {dt,4+dt,8+dt,12+dt} -> product in reg dt; stale rows
    // (other lanes' old Af) only touch regs we never read.
    float4v aA[4], aB[4];
    #pragma unroll
    for (int g = 0; g < 4; ++g)
      aA[g] = __builtin_amdgcn_mfma_f32_16x16x32_bf16(Af0, Bf[g][0], gxP[g], 0, 0, 0);
    #pragma unroll
    for (int g = 0; g < 4; ++g)
      aB[g] = __builtin_amdgcn_mfma_f32_16x16x32_bf16(Af2, Bf[g][2], z4, 0, 0, 0);
    #pragma unroll
    for (int g = 0; g < 4; ++g)
      aA[g] = __builtin_amdgcn_mfma_f32_16x16x32_bf16(Af1, Bf[g][1], aA[g], 0, 0, 0);
    #pragma unroll
    for (int g = 0; g < 4; ++g)
      aB[g] = __builtin_amdgcn_mfma_f32_16x16x32_bf16(Af3, Bf[g][3], aB[g], 0, 0, 0);

    post();   // safe: C-in (gxP) already consumed by the aA cluster above

    float gi = aA[0][dt] + aB[0][dt];
    float gf = aA[1][dt] + aB[1][dt];
    float gg = aA[2][dt] + aB[2][dt];
    float go = aA[3][dt] + aB[3][dt];
    // epilogue: 1 cell/lane (batch q, hidden hu). Shared-rcp pairs:
    // sig(i)*tanh(g) = e^i(e^2g-1) / [(1+e^i)(1+e^2g)], same for o/c.
    float ei  = fexp2(gi * LOG2E);
    float e2g = fexp2(gg * LOG2E2);
    float t1  = (ei * (e2g - 1.0f)) * frcp((1.0f + ei) * (1.0f + e2g));
    float sf  = fsig(gf);
    float c   = fmaf(sf, cst, t1);
    cst = c;
    float eo  = fexp2(go * LOG2E);
    float e2c = fexp2(fminf(c * LOG2E2, 126.0f));   // clamp: c can accumulate
    float h   = (eo * (e2c - 1.0f)) * frcp((1.0f + eo) * (1.0f + e2c));
    unsigned vv;
    asm("v_cvt_pk_bf16_f32 %0, %1, %2" : "=v"(vv) : "v"(h), "v"(zero_f));
    unsigned short hb16 = (unsigned short)vv;
    unsigned short* hw = (t & 1) ? hw0 : hw1;       // write buf (1-cur)
    hw[0] = hb16;
    if (hT_out && t == T-1) hT_out[((size_t)(bt0 + q))*H_ + hu] = h;
    // Raw barrier: drain LDS only; globals stay in flight (R7).
    __builtin_amdgcn_sched_barrier(0);
    asm volatile("s_waitcnt lgkmcnt(0)" ::: "memory");
    __builtin_amdgcn_s_barrier();
    __builtin_amdgcn_sched_barrier(0);
  };

  using I0 = std::integral_constant<int,0>;
  using I1 = std::integral_constant<int,1>;
  using I2 = std::integral_constant<int,2>;
  using I3 = std::integral_constant<int,3>;
  auto nop = []{};

  const int nwin = T >> 2, ntail = T & 3;
  for (int w = 0; w < nwin; ++w){
    const int t0 = w << 2;
    step(t0+0, I0{}, gxA, [&]{
      // gxB = gx(t0+4 .. t0+7); consumes nx loaded 3 steps ago.
      #pragma unroll
      for (int g = 0; g < 4; ++g){
        float4v tt = (float4v){bias[g], bias[g], bias[g], bias[g]};
        tt = __builtin_amdgcn_mfma_f32_16x16x32_bf16(nx0, Bf[g][4], tt, 0, 0, 0);
        gxB[g] = __builtin_amdgcn_mfma_f32_16x16x32_bf16(nx1, Bf[g][5], tt, 0, 0, 0);
      }
    }, nop);
    step(t0+1, I1{}, gxA, [&]{
      // issue loads for window w+2; consumed 3 steps later (dt=0 of w+1).
      const unsigned short* p = xwin(t0 + 8);
      nx0 = *(const short8*)p; nx1 = *(const short8*)(p + 32);
    }, nop);
    step(t0+2, I2{}, gxA, nop, nop);
    step(t0+3, I3{}, gxA, nop, [&]{
      // window rotation AFTER the cluster consumed gxA as C-in
      #pragma unroll
      for (int g = 0; g < 4; ++g) gxA[g] = gxB[g];
    });
  }
  // Tail (decoder T=1023: 3 steps). gxA already holds gx(nwin*4 ..).
  if (ntail > 0) step(nwin*4+0, I0{}, gxA, nop, nop);
  if (ntail > 1) step(nwin*4+1, I1{}, gxA, nop, nop);
  if (ntail > 2) step(nwin*4+2, I2{}, gxA, nop, nop);

  // Final out-head: h(T-1) is in buf[T&1] (written at step T-1, barrier-drained).
  if (do_out) out_head((T & 1) ? haR1 : haR0, T - 1);
}

// ---------------- Kernel C: mu/logvar/latent/dh0/dc0 ------------------------
__global__ __launch_bounds__(128) void latent_kernel(
    const float* __restrict__ hT, const float* __restrict__ eps,
    const float* __restrict__ mu_W, const float* __restrict__ mu_b,
    const float* __restrict__ mu_g, const float* __restrict__ mu_be,
    const float* __restrict__ lv_W, const float* __restrict__ lv_b,
    const float* __restrict__ lv_g, const float* __restrict__ lv_be,
    const float* __restrict__ lh_W, const float* __restrict__ lh_b,
    const float* __restrict__ lh_g, const float* __restrict__ lh_be,
    const float* __restrict__ lc_W, const float* __restrict__ lc_b,
    const float* __restrict__ lc_g, const float* __restrict__ lc_be,
    float* __restrict__ out, float* __restrict__ dh0, float* __restrict__ dc0)
{
  const int b = blockIdx.x, tid = threadIdx.x;
  const int wave = tid >> 6, lane = tid & 63;
  __shared__ float shT[H_];
  __shared__ float smu[L_], slv[L_], slat[L_];
  __shared__ float part[2];
  shT[tid] = hT[(size_t)b*H_ + tid];
  __syncthreads();
  {
    const float* W = wave ? lv_W : mu_W;
    float a = (wave ? lv_b : mu_b)[lane];
    for (int k = 0; k < H_; ++k) a += shT[k] * W[lane*H_ + k];
    a = leaky(a);
    float m = wredsum(a) * (1.0f/L_);
    float d = a - m;
    float v = wredsum(d*d) * (1.0f/L_);
    float y = d * rsqrtf(v + 1e-5f) * (wave ? lv_g : mu_g)[lane] + (wave ? lv_be : mu_be)[lane];
    out[(wave ? LV_OFF : MU_OFF) + (size_t)b*L_ + lane] = y;
    if (wave) slv[lane] = y; else smu[lane] = y;
  }
  __syncthreads();
  if (tid < L_) slat[tid] = smu[tid] + eps[(size_t)b*L_ + tid] * expf(0.5f*slv[tid]);
  __syncthreads();
  #pragma unroll 1
  for (int which = 0; which < 2; ++which){
    const float* W = which ? lc_W : lh_W;
    float p = (which ? lc_b : lh_b)[tid];
    for (int k = 0; k < L_; ++k) p += slat[k] * W[tid*L_ + k];
    p = leaky(p);
    float s = wredsum(p);
    if (lane == 0) part[wave] = s;
    __syncthreads();
    float mean = (part[0] + part[1]) * (1.0f/H_);
    __syncthreads();
    float d = p - mean;
    float s2 = wredsum(d*d);
    if (lane == 0) part[wave] = s2;
    __syncthreads();
    float var = (part[0] + part[1]) * (1.0f/H_);
    __syncthreads();
    float y = d * rsqrtf(var + 1e-5f) * (which ? lc_g : lh_g)[tid] + (which ? lc_be : lh_be)[tid];
    (which ? dc0 : dh0)[(size_t)b*H_ + tid] = y;
  }
}

// ---------------- launch ----------------------------------------------------
extern "C" void kernel_launch(void* const* d_in, const int* in_sizes, int n_in,
                              void* d_out, int out_size, void* d_ws, size_t ws_size,
                              hipStream_t stream)
{
  (void)in_sizes; (void)n_in; (void)out_size; (void)ws_size;
  const float* x       = (const float*)d_in[0];
  const float* eps     = (const float*)d_in[1];
  const float* init_W  = (const float*)d_in[2];
  const float* init_b  = (const float*)d_in[3];
  const float* init_g  = (const float*)d_in[4];
  const float* init_be = (const float*)d_in[5];
  const float* enc_Wih = (const float*)d_in[6];
  const float* enc_Whh = (const float*)d_in[7];
  const float* enc_bih = (const float*)d_in[8];
  const float* enc_bhh = (const float*)d_in[9];
  const float* mu_W  = (const float*)d_in[10];
  const float* mu_b  = (const float*)d_in[11];
  const float* mu_g  = (const float*)d_in[12];
  const float* mu_be = (const float*)d_in[13];
  const float* lv_W  = (const float*)d_in[14];
  const float* lv_b  = (const float*)d_in[15];
  const float* lv_g  = (const float*)d_in[16];
  const float* lv_be = (const float*)d_in[17];
  const float* dec_Wih = (const float*)d_in[18];
  const float* dec_Whh = (const float*)d_in[19];
  const float* dec_bih = (const float*)d_in[20];
  const float* dec_bhh = (const float*)d_in[21];
  const float* lh_W  = (const float*)d_in[22];
  const float* lh_b  = (const float*)d_in[23];
  const float* lh_g  = (const float*)d_in[24];
  const float* lh_be = (const float*)d_in[25];
  const float* lc_W  = (const float*)d_in[26];
  const float* lc_b  = (const float*)d_in[27];
  const float* lc_g  = (const float*)d_in[28];
  const float* lc_be = (const float*)d_in[29];
  const float* act_W  = (const float*)d_in[30];
  const float* act_b  = (const float*)d_in[31];
  const float* time_W = (const float*)d_in[32];
  const float* time_b = (const float*)d_in[33];
  float* out = (float*)d_out;

  // workspace: xemb [1024][256][64] bf16 + 64-short zero pad, hT, dh0, dc0
  unsigned short* xemb = (unsigned short*)d_ws;
  float* hT  = (float*)(xemb + (size_t)S_*B_*E_ + 64);
  float* dh0 = hT  + B_*H_;
  float* dc0 = dh0 + B_*H_;

  init_kernel<<<dim3((B_*S_)/(4*INIT_ROWS)), dim3(256), 0, stream>>>(
      x, init_W, init_b, init_g, init_be, xemb);

  lstm_kernel<<<dim3(64), dim3(512), 0, stream>>>(
      enc_Wih, enc_Whh, enc_bih, enc_bhh, xemb, S_,
      nullptr, nullptr, hT,
      nullptr, nullptr, nullptr, nullptr, nullptr);

  latent_kernel<<<dim3(B_), dim3(128), 0, stream>>>(
      hT, eps, mu_W, mu_b, mu_g, mu_be, lv_W, lv_b, lv_g, lv_be,
      lh_W, lh_b, lh_g, lh_be, lc_W, lc_b, lc_g, lc_be, out, dh0, dc0);

  lstm_kernel<<<dim3(64), dim3(512), 0, stream>>>(
      dec_Wih, dec_Whh, dec_bih, dec_bhh, xemb, S_-1,
      dh0, dc0, nullptr,
      out, act_W, act_b, time_W, time_b);
}

// Round 11
// 1202.638 us; speedup vs baseline: 1.0859x; 1.0143x over previous
//
#include <hip/hip_runtime.h>
#include <hip/hip_bf16.h>
#include <type_traits>

// LogVAE. R17 (post-mortem R16: per-step fused head cost +81us on the
//  barrier-critical path — 4-deep MFMA chain every step. R13 remains best
//  lstm structure @491us/dispatch).
//  R17 = MEGAKERNEL: enc lstm -> in-WG latent -> dec lstm, one dispatch.
//  Each WG owns 4 batches end-to-end (embarrassingly parallel): hT, dh0,
//  dc0 never leave LDS; latent/out_kernel dispatches and hs buffer gone.
//  Fused out-head is TIME-BATCHED (gx trick): h(t) also written to a
//  window-parity double-buffered history tile [4b+dt][128]; once per 4
//  steps waves 0/1 do 4 MFMAs covering 4 timesteps (reads+MFMAs in dt=2's
//  empty pre-slot, stores at dt=3 — chain latency off the critical path).
//  lstm core otherwise byte-equivalent to R13 (lane-rotated reg-dt, gx
//  C-in, K-split, lgkmcnt-only barrier).

#define B_ 256
#define S_ 1024
#define NF_ 32
#define E_ 64
#define H_ 128
#define L_ 64
#define C_ 31

#define ACTS_OFF 0
#define TS_OFF   8118528   // 256*1023*31
#define MU_OFF   8380416   // + 256*1023
#define LV_OFF   8396800   // + 256*64

#define LOG2E  1.44269504f
#define LOG2E2 2.88539008f

typedef __attribute__((ext_vector_type(8))) short short8;
typedef __attribute__((ext_vector_type(4))) float float4v;

__device__ inline unsigned short f2bf(float x){
  union { float f; unsigned u; } a; a.f = x;
  unsigned r = a.u + 0x7FFFu + ((a.u >> 16) & 1u);
  return (unsigned short)(r >> 16);
}
__device__ inline float frcp(float x){
#if __has_builtin(__builtin_amdgcn_rcpf)
  return __builtin_amdgcn_rcpf(x);
#else
  return 1.0f / x;
#endif
}
__device__ inline float fexp2(float x){
#if __has_builtin(__builtin_amdgcn_exp2f)
  return __builtin_amdgcn_exp2f(x);
#else
  return exp2f(x);
#endif
}
__device__ inline float fsig(float x){ return frcp(1.0f + fexp2(-LOG2E*x)); }
__device__ inline float leaky(float x){ return x >= 0.0f ? x : 0.01f*x; }
__device__ inline float wredsum(float v){
  v += __shfl_xor(v, 32, 64);
  v += __shfl_xor(v, 16, 64);
  v += __shfl_xor(v,  8, 64);
  v += __shfl_xor(v,  4, 64);
  v += __shfl_xor(v,  2, 64);
  v += __shfl_xor(v,  1, 64);
  return v;
}

// ---------------- Kernel A: x_emb = LN(leaky(x @ W.T + b)) -> bf16 [S][B][E] --
#define INIT_ROWS 16
__global__ __launch_bounds__(256) void init_kernel(
    const float* __restrict__ x, const float* __restrict__ W,
    const float* __restrict__ bias, const float* __restrict__ gam,
    const float* __restrict__ beta, unsigned short* __restrict__ xemb)
{
  if (blockIdx.x == 0 && threadIdx.x < 64)
    xemb[(size_t)S_*B_*E_ + threadIdx.x] = 0;

  const int wave = threadIdx.x >> 6, lane = threadIdx.x & 63;
  float wf[NF_];
  {
    const float4* wr = (const float4*)(W + lane * NF_);
    #pragma unroll
    for (int j = 0; j < NF_/4; ++j){
      float4 t = wr[j];
      wf[4*j+0] = t.x; wf[4*j+1] = t.y; wf[4*j+2] = t.z; wf[4*j+3] = t.w;
    }
  }
  const float bb = bias[lane], gg = gam[lane], be = beta[lane];

  const int r0 = (blockIdx.x * 4 + wave) * INIT_ROWS;
  for (int rr = 0; rr < INIT_ROWS; ++rr){
    const int ru = __builtin_amdgcn_readfirstlane(r0 + rr);  // wave-uniform row
    const int b = ru >> 10, s = ru & 1023;
    const float* xr = x + (size_t)ru * NF_;   // SGPR-based -> s_loads
    float acc = bb;
    #pragma unroll
    for (int k = 0; k < NF_; ++k)
      acc = fmaf(xr[k], wf[k], acc);
    acc = leaky(acc);
    float m = wredsum(acc) * (1.0f/64.0f);
    float d = acc - m;
    float v = wredsum(d*d) * (1.0f/64.0f);
    float y = d * rsqrtf(v + 1e-5f) * gg + be;
    xemb[((size_t)s * B_ + b) * E_ + lane] = f2bf(y);   // [S][B][E]
  }
}

// ---------------- Megakernel: enc lstm -> latent -> dec lstm (+out heads) ----
// grid=64 (4 batch/WG), block=512 (8 waves). lstm core = R13 structure.
__global__ __launch_bounds__(512, 2) void mega_kernel(
    const unsigned short* __restrict__ xemb,  // [S][256][64] bf16 (+64 pad)
    const float* __restrict__ encWih, const float* __restrict__ encWhh,
    const float* __restrict__ encbih, const float* __restrict__ encbhh,
    const float* __restrict__ decWih, const float* __restrict__ decWhh,
    const float* __restrict__ decbih, const float* __restrict__ decbhh,
    const float* __restrict__ eps,
    const float* __restrict__ mu_W, const float* __restrict__ mu_b,
    const float* __restrict__ mu_g, const float* __restrict__ mu_be,
    const float* __restrict__ lv_W, const float* __restrict__ lv_b,
    const float* __restrict__ lv_g, const float* __restrict__ lv_be,
    const float* __restrict__ lh_W, const float* __restrict__ lh_b,
    const float* __restrict__ lh_g, const float* __restrict__ lh_be,
    const float* __restrict__ lc_W, const float* __restrict__ lc_b,
    const float* __restrict__ lc_g, const float* __restrict__ lc_be,
    const float* __restrict__ actW, const float* __restrict__ actB,
    const float* __restrict__ timeW, const float* __restrict__ timeB,
    float* __restrict__ out)
{
  __shared__ unsigned short hbuf[2][16*136];  // recurrence ping-pong (+8 pad/row)
  __shared__ unsigned short hist[2][16*136];  // h history, window-parity dbuf
  __shared__ float shT[4][H_];                // enc hT (f32)
  __shared__ float sml[4][2*L_];              // mu|lv per batch
  __shared__ float slat[4][L_];
  __shared__ float sdh[4][H_], sdc[4][H_];
  __shared__ float partA[8];

  const int tid = threadIdx.x;
  const int wave = tid >> 6, lane = tid & 63;
  const int q = lane >> 4, c16 = lane & 15;
  const int bt0 = blockIdx.x * 4;
  const int hu = wave * 16 + c16;
  unsigned short* hflat = &hbuf[0][0];
  unsigned short* histf = &hist[0][0];
  const float4v z4 = (float4v){0.0f, 0.0f, 0.0f, 0.0f};
  float zero_f = 0.0f;

  for (int idx = tid; idx < 2*16*136; idx += 512) hflat[idx] = 0;
  __syncthreads();

  // x window machinery (shared by both phases). Lane A-row = c16 = 4*b + dt.
  const int xb = c16 >> 2, xdt = c16 & 3;
  const unsigned short* xbase = xemb + ((size_t)(bt0 + xb))*E_ + q*8;
  const size_t xrow = (size_t)B_*E_;

  using I0 = std::integral_constant<int,0>;
  using I1 = std::integral_constant<int,1>;
  using I2 = std::integral_constant<int,2>;
  using I3 = std::integral_constant<int,3>;
  auto nop = []{};

  // ================= LSTM runner (enc: DEC=false / dec: DEC=true) ==========
  auto run = [&](const float* Wih, const float* Whh, const float* bih,
                 const float* bhh, int T, auto decc){
    constexpr bool DEC = decltype(decc)::value;

    // Persistent B frags: kb 0..3 = Whh (K=0..128), kb 4..5 = Wih (K=128..192)
    short8 Bf[4][6];
    float bias[4];
    #pragma unroll
    for (int g = 0; g < 4; ++g){
      const int gcol = g*128 + hu;
      bias[g] = bih[gcol] + bhh[gcol];
      #pragma unroll
      for (int kb = 0; kb < 6; ++kb){
        union { short8 v; unsigned short u[8]; } tmp;
        #pragma unroll
        for (int j = 0; j < 8; ++j){
          int k = kb*32 + q*8 + j;
          float wv = (kb < 4) ? Whh[gcol*H_ + k] : Wih[gcol*E_ + (k - H_)];
          tmp.u[j] = f2bf(wv);
        }
        Bf[g][kb] = tmp.v;
      }
    }

    // Fused out-head frags (decoder, waves 0/1): n = wave*16 + c16.
    const bool do_head = DEC && (wave < 2);
    short8 Of0 = 0, Of1 = 0, Of2 = 0, Of3 = 0;
    float obias = 0.0f;
    if (do_head){
      const int n = wave*16 + c16;
      obias = (n < C_) ? actB[n] : timeB[0];
      union { short8 v; unsigned short u[8]; } tmp[4];
      #pragma unroll
      for (int kb = 0; kb < 4; ++kb)
        #pragma unroll
        for (int j = 0; j < 8; ++j){
          int k = kb*32 + q*8 + j;
          tmp[kb].u[j] = f2bf((n < C_) ? actW[n*H_ + k] : timeW[k]);
        }
      Of0 = tmp[0].v; Of1 = tmp[1].v; Of2 = tmp[2].v; Of3 = tmp[3].v;
    }
    short8 Ph0 = 0, Ph1 = 0, Ph2 = 0, Ph3 = 0;   // captured history A-frags
    float4v oacc = z4;                            // pending head outputs

    // h0/c0: buf0 rows {0,4,8,12} (other rows stay zero from initial memset)
    {
      int b = tid >> 7, k = tid & 127;   // 512 = 4*128
      hbuf[0][(4*b)*136 + k] = DEC ? f2bf(sdh[b][k]) : (unsigned short)0x3F80;
    }
    float cst = DEC ? sdc[q][hu] : 0.0f;
    __syncthreads();

    auto xwin = [&](int wt)->const unsigned short*{
      int tt = wt + xdt; if (tt > T-1) tt = T-1;   // clamp: garbage rows unused
      return xbase + (size_t)tt * xrow;
    };

    // Prologue: gxA = gx(0..3); nx = x(4..7) in flight.
    float4v gxA[4], gxB[4];
    short8 nx0, nx1;
    { const unsigned short* p = xwin(0);
      nx0 = *(const short8*)p; nx1 = *(const short8*)(p + 32); }
    #pragma unroll
    for (int g = 0; g < 4; ++g){
      float4v t = (float4v){bias[g], bias[g], bias[g], bias[g]};
      t = __builtin_amdgcn_mfma_f32_16x16x32_bf16(nx0, Bf[g][4], t, 0, 0, 0);
      gxA[g] = __builtin_amdgcn_mfma_f32_16x16x32_bf16(nx1, Bf[g][5], t, 0, 0, 0);
    }
    { const unsigned short* p = xwin(4);
      nx0 = *(const short8*)p; nx1 = *(const short8*)(p + 32); }

    short8 Af0 = 0, Af1 = 0, Af2 = 0, Af3 = 0;

    const unsigned short* haR0 = hflat + (c16 & ~3)*136 + q*8;  // buf0
    const unsigned short* haR1 = haR0 + 2176;                   // buf1
    unsigned short* hw0 = hflat + (4*q)*136 + hu;               // write buf0
    unsigned short* hw1 = hw0 + 2176;                           // write buf1

    // step: R13 core + (DEC) history write to window-parity buffer.
    auto step = [&](int t, auto dtc, float4v (&gxP)[4], auto&& pre, auto&& post){
      constexpr int dt = decltype(dtc)::value;
      const unsigned short* ha = (t & 1) ? haR1 : haR0;
      if ((c16 & 3) == dt){            // this step's h-supplier lanes
        Af0 = *(const short8*)(ha);
        Af1 = *(const short8*)(ha + 32);
        Af2 = *(const short8*)(ha + 64);
        Af3 = *(const short8*)(ha + 96);
      }
      pre();

      float4v aA[4], aB[4];
      #pragma unroll
      for (int g = 0; g < 4; ++g)
        aA[g] = __builtin_amdgcn_mfma_f32_16x16x32_bf16(Af0, Bf[g][0], gxP[g], 0, 0, 0);
      #pragma unroll
      for (int g = 0; g < 4; ++g)
        aB[g] = __builtin_amdgcn_mfma_f32_16x16x32_bf16(Af2, Bf[g][2], z4, 0, 0, 0);
      #pragma unroll
      for (int g = 0; g < 4; ++g)
        aA[g] = __builtin_amdgcn_mfma_f32_16x16x32_bf16(Af1, Bf[g][1], aA[g], 0, 0, 0);
      #pragma unroll
      for (int g = 0; g < 4; ++g)
        aB[g] = __builtin_amdgcn_mfma_f32_16x16x32_bf16(Af3, Bf[g][3], aB[g], 0, 0, 0);

      post();   // safe: C-in (gxP) consumed above

      float gi = aA[0][dt] + aB[0][dt];
      float gf = aA[1][dt] + aB[1][dt];
      float gg = aA[2][dt] + aB[2][dt];
      float go = aA[3][dt] + aB[3][dt];
      float ei  = fexp2(gi * LOG2E);
      float e2g = fexp2(gg * LOG2E2);
      float t1  = (ei * (e2g - 1.0f)) * frcp((1.0f + ei) * (1.0f + e2g));
      float sf  = fsig(gf);
      float c   = fmaf(sf, cst, t1);
      cst = c;
      float eo  = fexp2(go * LOG2E);
      float e2c = fexp2(fminf(c * LOG2E2, 126.0f));
      float h   = (eo * (e2c - 1.0f)) * frcp((1.0f + eo) * (1.0f + e2c));
      unsigned vv;
      asm("v_cvt_pk_bf16_f32 %0, %1, %2" : "=v"(vv) : "v"(h), "v"(zero_f));
      unsigned short hb16 = (unsigned short)vv;
      unsigned short* hw = (t & 1) ? hw0 : hw1;
      hw[0] = hb16;
      if (DEC)   // history: row 4q+dt of window-parity buffer
        histf[((t >> 2) & 1)*2176 + (4*q + dt)*136 + hu] = hb16;
      if (!DEC && t == T-1) shT[q][hu] = h;   // enc hT capture (f32, LDS)
      __builtin_amdgcn_sched_barrier(0);
      asm volatile("s_waitcnt lgkmcnt(0)" ::: "memory");
      __builtin_amdgcn_s_barrier();
      __builtin_amdgcn_sched_barrier(0);
    };

    // head helpers (waves 0/1): capture+4 MFMAs from hist buffer `par`.
    auto head_mfma = [&](int par){
      const unsigned short* hb = histf + par*2176 + c16*136 + q*8;
      Ph0 = *(const short8*)(hb);
      Ph1 = *(const short8*)(hb + 32);
      Ph2 = *(const short8*)(hb + 64);
      Ph3 = *(const short8*)(hb + 96);
      float4v o = (float4v){obias, obias, obias, obias};
      o = __builtin_amdgcn_mfma_f32_16x16x32_bf16(Ph0, Of0, o, 0, 0, 0);
      o = __builtin_amdgcn_mfma_f32_16x16x32_bf16(Ph1, Of1, o, 0, 0, 0);
      o = __builtin_amdgcn_mfma_f32_16x16x32_bf16(Ph2, Of2, o, 0, 0, 0);
      o = __builtin_amdgcn_mfma_f32_16x16x32_bf16(Ph3, Of3, o, 0, 0, 0);
      oacc = o;
    };
    auto head_store = [&](int tb, int cnt){
      const int n = wave*16 + c16;
      const size_t bq = (size_t)(bt0 + q);
      if (n < C_){
        #pragma unroll
        for (int r = 0; r < 4; ++r)
          if (r < cnt) out[ACTS_OFF + (bq*(size_t)(S_-1) + (size_t)(tb + r))*C_ + n] = oacc[r];
      } else {
        #pragma unroll
        for (int r = 0; r < 4; ++r)
          if (r < cnt) out[TS_OFF + bq*(size_t)(S_-1) + (size_t)(tb + r)] = oacc[r];
      }
    };

    const int nwin = T >> 2, ntail = T & 3;
    for (int w = 0; w < nwin; ++w){
      const int t0 = w << 2;
      step(t0+0, I0{}, gxA, [&]{
        #pragma unroll
        for (int g = 0; g < 4; ++g){
          float4v tt = (float4v){bias[g], bias[g], bias[g], bias[g]};
          tt = __builtin_amdgcn_mfma_f32_16x16x32_bf16(nx0, Bf[g][4], tt, 0, 0, 0);
          gxB[g] = __builtin_amdgcn_mfma_f32_16x16x32_bf16(nx1, Bf[g][5], tt, 0, 0, 0);
        }
      }, nop);
      step(t0+1, I1{}, gxA, [&]{
        const unsigned short* p = xwin(t0 + 8);
        nx0 = *(const short8*)p; nx1 = *(const short8*)(p + 32);
      }, nop);
      step(t0+2, I2{}, gxA, [&]{
        // head for window w-1 (hist buf (w-1)&1 complete & stable: dbuf)
        if (do_head && w > 0) head_mfma((w-1) & 1);
      }, nop);
      step(t0+3, I3{}, gxA, [&]{
        if (do_head && w > 0) head_store((w-1)*4, 4);  // chain had a full step
      }, [&]{
        #pragma unroll
        for (int g = 0; g < 4; ++g) gxA[g] = gxB[g];
      });
    }
    // Tail (dec T=1023: 3 steps). gxA holds gx(nwin*4 ..).
    if (ntail > 0) step(nwin*4+0, I0{}, gxA, [&]{
        if (do_head) head_mfma((nwin-1) & 1);          // last full window
      }, nop);
    if (ntail > 1) step(nwin*4+1, I1{}, gxA, [&]{
        if (do_head) head_store((nwin-1)*4, 4);
      }, nop);
    if (ntail > 2) step(nwin*4+2, I2{}, gxA, nop, nop);
    // Final partial head: hist buf nwin&1 rows 0..ntail-1 = h(nwin*4 ..).
    if (do_head && ntail > 0){
      head_mfma(nwin & 1);
      head_store(nwin*4, ntail);
    }
  };

  // ======================= ENCODER =======================
  run(encWih, encWhh, encbih, encbhh, S_, std::integral_constant<bool,false>{});

  // ======================= LATENT (in-WG, 4 batches) =====
  {
    const int bb = tid >> 7, slot = tid & 127;
    const int unit = slot & 63;
    const bool isLv = slot >= 64;
    // mu/lv: per-wave LN over 64 units (wave == (bb,isLv) group exactly)
    const float* W = isLv ? lv_W : mu_W;
    float a = (isLv ? lv_b : mu_b)[unit];
    const float4* wr = (const float4*)(W + unit*H_);
    #pragma unroll 4
    for (int j = 0; j < H_/4; ++j){
      float4 w4 = wr[j];
      a += w4.x*shT[bb][4*j] + w4.y*shT[bb][4*j+1]
         + w4.z*shT[bb][4*j+2] + w4.w*shT[bb][4*j+3];
    }
    a = leaky(a);
    float m = wredsum(a) * (1.0f/L_);
    float d = a - m;
    float v = wredsum(d*d) * (1.0f/L_);
    float y = d * rsqrtf(v + 1e-5f) * (isLv ? lv_g : mu_g)[unit]
            + (isLv ? lv_be : mu_be)[unit];
    out[(isLv ? LV_OFF : MU_OFF) + (size_t)(bt0 + bb)*L_ + unit] = y;
    sml[bb][slot] = y;
    __syncthreads();
    if (!isLv)
      slat[bb][unit] = sml[bb][unit]
                     + eps[(size_t)(bt0 + bb)*L_ + unit] * expf(0.5f*sml[bb][64 + unit]);
    __syncthreads();
    // dh0/dc0: LN over 128 units (waves 2bb / 2bb+1)
    #pragma unroll 1
    for (int which = 0; which < 2; ++which){
      const float* W2 = which ? lc_W : lh_W;
      float p = (which ? lc_b : lh_b)[slot];
      const float4* w2 = (const float4*)(W2 + slot*L_);
      #pragma unroll 4
      for (int j = 0; j < L_/4; ++j){
        float4 w4 = w2[j];
        p += w4.x*slat[bb][4*j] + w4.y*slat[bb][4*j+1]
           + w4.z*slat[bb][4*j+2] + w4.w*slat[bb][4*j+3];
      }
      p = leaky(p);
      float s = wredsum(p);
      if (lane == 0) partA[wave] = s;
      __syncthreads();
      float mean = (partA[2*bb] + partA[2*bb+1]) * (1.0f/H_);
      __syncthreads();
      float dd = p - mean;
      float s2 = wredsum(dd*dd);
      if (lane == 0) partA[wave] = s2;
      __syncthreads();
      float var = (partA[2*bb] + partA[2*bb+1]) * (1.0f/H_);
      __syncthreads();
      float yy = dd * rsqrtf(var + 1e-5f) * (which ? lc_g : lh_g)[slot]
               + (which ? lc_be : lh_be)[slot];
      (which ? sdc : sdh)[bb][slot] = yy;
    }
  }
  __syncthreads();

  // ======================= DECODER (+fused heads) ========
  run(decWih, decWhh, decbih, decbhh, S_-1, std::integral_constant<bool,true>{});
}

// ---------------- launch ----------------------------------------------------
extern "C" void kernel_launch(void* const* d_in, const int* in_sizes, int n_in,
                              void* d_out, int out_size, void* d_ws, size_t ws_size,
                              hipStream_t stream)
{
  (void)in_sizes; (void)n_in; (void)out_size; (void)ws_size;
  const float* x       = (const float*)d_in[0];
  const float* eps     = (const float*)d_in[1];
  const float* init_W  = (const float*)d_in[2];
  const float* init_b  = (const float*)d_in[3];
  const float* init_g  = (const float*)d_in[4];
  const float* init_be = (const float*)d_in[5];
  const float* enc_Wih = (const float*)d_in[6];
  const float* enc_Whh = (const float*)d_in[7];
  const float* enc_bih = (const float*)d_in[8];
  const float* enc_bhh = (const float*)d_in[9];
  const float* mu_W  = (const float*)d_in[10];
  const float* mu_b  = (const float*)d_in[11];
  const float* mu_g  = (const float*)d_in[12];
  const float* mu_be = (const float*)d_in[13];
  const float* lv_W  = (const float*)d_in[14];
  const float* lv_b  = (const float*)d_in[15];
  const float* lv_g  = (const float*)d_in[16];
  const float* lv_be = (const float*)d_in[17];
  const float* dec_Wih = (const float*)d_in[18];
  const float* dec_Whh = (const float*)d_in[19];
  const float* dec_bih = (const float*)d_in[20];
  const float* dec_bhh = (const float*)d_in[21];
  const float* lh_W  = (const float*)d_in[22];
  const float* lh_b  = (const float*)d_in[23];
  const float* lh_g  = (const float*)d_in[24];
  const float* lh_be = (const float*)d_in[25];
  const float* lc_W  = (const float*)d_in[26];
  const float* lc_b  = (const float*)d_in[27];
  const float* lc_g  = (const float*)d_in[28];
  const float* lc_be = (const float*)d_in[29];
  const float* act_W  = (const float*)d_in[30];
  const float* act_b  = (const float*)d_in[31];
  const float* time_W = (const float*)d_in[32];
  const float* time_b = (const float*)d_in[33];
  float* out = (float*)d_out;

  // workspace: xemb [1024][256][64] bf16 + 64-short zero pad
  unsigned short* xemb = (unsigned short*)d_ws;

  init_kernel<<<dim3((B_*S_)/(4*INIT_ROWS)), dim3(256), 0, stream>>>(
      x, init_W, init_b, init_g, init_be, xemb);

  mega_kernel<<<dim3(64), dim3(512), 0, stream>>>(
      xemb,
      enc_Wih, enc_Whh, enc_bih, enc_bhh,
      dec_Wih, dec_Whh, dec_bih, dec_bhh,
      eps,
      mu_W, mu_b, mu_g, mu_be,
      lv_W, lv_b, lv_g, lv_be,
      lh_W, lh_b, lh_g, lh_be,
      lc_W, lc_b, lc_g, lc_be,
      act_W, act_b, time_W, time_b,
      out);
}

// Round 12
// 1164.739 us; speedup vs baseline: 1.1212x; 1.0325x over previous
//
#include <hip/hip_runtime.h>
#include <hip/hip_bf16.h>
#include <type_traits>

// LogVAE. R18 (post-mortem R17: time-batched in-loop head cost the SAME
//  ~70us as R16's per-step head — ANY work added to the barrier-locked step
//  loop costs ~70us (critical-wave issue + lgkmcnt-drained LDS traffic);
//  R13's global hs stores are fire-and-forget (vmcnt never drained in-loop)
//  and measured FREE (dec 491us == enc 491us despite 65MB stores)).
//  R18 = megakernel WITHOUT in-loop heads: enc lstm -> in-WG latent ->
//  dec lstm writing hs (global, free) -> separate out_kernel (256-CU
//  throughput, ~35us). Keeps R17's real wins: latent fused (no hT/dh0/dc0
//  round-trips, 2 fewer dispatch gaps). lstm step loop = R13 verbatim.

#define B_ 256
#define S_ 1024
#define NF_ 32
#define E_ 64
#define H_ 128
#define L_ 64
#define C_ 31

#define ACTS_OFF 0
#define TS_OFF   8118528   // 256*1023*31
#define MU_OFF   8380416   // + 256*1023
#define LV_OFF   8396800   // + 256*64

#define LOG2E  1.44269504f
#define LOG2E2 2.88539008f

typedef __attribute__((ext_vector_type(8))) short short8;
typedef __attribute__((ext_vector_type(4))) float float4v;

__device__ inline unsigned short f2bf(float x){
  union { float f; unsigned u; } a; a.f = x;
  unsigned r = a.u + 0x7FFFu + ((a.u >> 16) & 1u);
  return (unsigned short)(r >> 16);
}
__device__ inline float frcp(float x){
#if __has_builtin(__builtin_amdgcn_rcpf)
  return __builtin_amdgcn_rcpf(x);
#else
  return 1.0f / x;
#endif
}
__device__ inline float fexp2(float x){
#if __has_builtin(__builtin_amdgcn_exp2f)
  return __builtin_amdgcn_exp2f(x);
#else
  return exp2f(x);
#endif
}
__device__ inline float fsig(float x){ return frcp(1.0f + fexp2(-LOG2E*x)); }
__device__ inline float leaky(float x){ return x >= 0.0f ? x : 0.01f*x; }
__device__ inline float wredsum(float v){
  v += __shfl_xor(v, 32, 64);
  v += __shfl_xor(v, 16, 64);
  v += __shfl_xor(v,  8, 64);
  v += __shfl_xor(v,  4, 64);
  v += __shfl_xor(v,  2, 64);
  v += __shfl_xor(v,  1, 64);
  return v;
}

// ---------------- Kernel A: x_emb = LN(leaky(x @ W.T + b)) -> bf16 [S][B][E] --
#define INIT_ROWS 16
__global__ __launch_bounds__(256) void init_kernel(
    const float* __restrict__ x, const float* __restrict__ W,
    const float* __restrict__ bias, const float* __restrict__ gam,
    const float* __restrict__ beta, unsigned short* __restrict__ xemb)
{
  if (blockIdx.x == 0 && threadIdx.x < 64)
    xemb[(size_t)S_*B_*E_ + threadIdx.x] = 0;

  const int wave = threadIdx.x >> 6, lane = threadIdx.x & 63;
  float wf[NF_];
  {
    const float4* wr = (const float4*)(W + lane * NF_);
    #pragma unroll
    for (int j = 0; j < NF_/4; ++j){
      float4 t = wr[j];
      wf[4*j+0] = t.x; wf[4*j+1] = t.y; wf[4*j+2] = t.z; wf[4*j+3] = t.w;
    }
  }
  const float bb = bias[lane], gg = gam[lane], be = beta[lane];

  const int r0 = (blockIdx.x * 4 + wave) * INIT_ROWS;
  for (int rr = 0; rr < INIT_ROWS; ++rr){
    const int ru = __builtin_amdgcn_readfirstlane(r0 + rr);  // wave-uniform row
    const int b = ru >> 10, s = ru & 1023;
    const float* xr = x + (size_t)ru * NF_;   // SGPR-based -> s_loads
    float acc = bb;
    #pragma unroll
    for (int k = 0; k < NF_; ++k)
      acc = fmaf(xr[k], wf[k], acc);
    acc = leaky(acc);
    float m = wredsum(acc) * (1.0f/64.0f);
    float d = acc - m;
    float v = wredsum(d*d) * (1.0f/64.0f);
    float y = d * rsqrtf(v + 1e-5f) * gg + be;
    xemb[((size_t)s * B_ + b) * E_ + lane] = f2bf(y);   // [S][B][E]
  }
}

// ---------------- Megakernel: enc lstm -> latent -> dec lstm -----------------
// grid=64 (4 batch/WG), block=512 (8 waves). lstm core = R13 structure.
__global__ __launch_bounds__(512, 2) void mega_kernel(
    const unsigned short* __restrict__ xemb,  // [S][256][64] bf16 (+64 pad)
    const float* __restrict__ encWih, const float* __restrict__ encWhh,
    const float* __restrict__ encbih, const float* __restrict__ encbhh,
    const float* __restrict__ decWih, const float* __restrict__ decWhh,
    const float* __restrict__ decbih, const float* __restrict__ decbhh,
    const float* __restrict__ eps,
    const float* __restrict__ mu_W, const float* __restrict__ mu_b,
    const float* __restrict__ mu_g, const float* __restrict__ mu_be,
    const float* __restrict__ lv_W, const float* __restrict__ lv_b,
    const float* __restrict__ lv_g, const float* __restrict__ lv_be,
    const float* __restrict__ lh_W, const float* __restrict__ lh_b,
    const float* __restrict__ lh_g, const float* __restrict__ lh_be,
    const float* __restrict__ lc_W, const float* __restrict__ lc_b,
    const float* __restrict__ lc_g, const float* __restrict__ lc_be,
    unsigned short* __restrict__ hs,          // [S-1][256][128] bf16
    float* __restrict__ out)
{
  __shared__ unsigned short hbuf[2][16*136];  // recurrence ping-pong (+8 pad/row)
  __shared__ float shT[4][H_];                // enc hT (f32)
  __shared__ float sml[4][2*L_];              // mu|lv per batch
  __shared__ float slat[4][L_];
  __shared__ float sdh[4][H_], sdc[4][H_];
  __shared__ float partA[8];

  const int tid = threadIdx.x;
  const int wave = tid >> 6, lane = tid & 63;
  const int q = lane >> 4, c16 = lane & 15;
  const int bt0 = blockIdx.x * 4;
  const int hu = wave * 16 + c16;
  unsigned short* hflat = &hbuf[0][0];
  const float4v z4 = (float4v){0.0f, 0.0f, 0.0f, 0.0f};
  float zero_f = 0.0f;

  for (int idx = tid; idx < 2*16*136; idx += 512) hflat[idx] = 0;
  __syncthreads();

  // x window machinery (shared by both phases). Lane A-row = c16 = 4*b + dt.
  const int xb = c16 >> 2, xdt = c16 & 3;
  const unsigned short* xbase = xemb + ((size_t)(bt0 + xb))*E_ + q*8;
  const size_t xrow = (size_t)B_*E_;

  using I0 = std::integral_constant<int,0>;
  using I1 = std::integral_constant<int,1>;
  using I2 = std::integral_constant<int,2>;
  using I3 = std::integral_constant<int,3>;
  auto nop = []{};

  // ================= LSTM runner (enc: DEC=false / dec: DEC=true) ==========
  auto run = [&](const float* Wih, const float* Whh, const float* bih,
                 const float* bhh, int T, auto decc){
    constexpr bool DEC = decltype(decc)::value;

    // Persistent B frags: kb 0..3 = Whh (K=0..128), kb 4..5 = Wih (K=128..192)
    short8 Bf[4][6];
    float bias[4];
    #pragma unroll
    for (int g = 0; g < 4; ++g){
      const int gcol = g*128 + hu;
      bias[g] = bih[gcol] + bhh[gcol];
      #pragma unroll
      for (int kb = 0; kb < 6; ++kb){
        union { short8 v; unsigned short u[8]; } tmp;
        #pragma unroll
        for (int j = 0; j < 8; ++j){
          int k = kb*32 + q*8 + j;
          float wv = (kb < 4) ? Whh[gcol*H_ + k] : Wih[gcol*E_ + (k - H_)];
          tmp.u[j] = f2bf(wv);
        }
        Bf[g][kb] = tmp.v;
      }
    }

    // h0/c0: buf0 rows {0,4,8,12} (other rows stay zero from initial memset)
    {
      int b = tid >> 7, k = tid & 127;   // 512 = 4*128
      hbuf[0][(4*b)*136 + k] = DEC ? f2bf(sdh[b][k]) : (unsigned short)0x3F80;
    }
    float cst = DEC ? sdc[q][hu] : 0.0f;
    __syncthreads();

    auto xwin = [&](int wt)->const unsigned short*{
      int tt = wt + xdt; if (tt > T-1) tt = T-1;   // clamp: garbage rows unused
      return xbase + (size_t)tt * xrow;
    };

    // Prologue: gxA = gx(0..3); nx = x(4..7) in flight.
    float4v gxA[4], gxB[4];
    short8 nx0, nx1;
    { const unsigned short* p = xwin(0);
      nx0 = *(const short8*)p; nx1 = *(const short8*)(p + 32); }
    #pragma unroll
    for (int g = 0; g < 4; ++g){
      float4v t = (float4v){bias[g], bias[g], bias[g], bias[g]};
      t = __builtin_amdgcn_mfma_f32_16x16x32_bf16(nx0, Bf[g][4], t, 0, 0, 0);
      gxA[g] = __builtin_amdgcn_mfma_f32_16x16x32_bf16(nx1, Bf[g][5], t, 0, 0, 0);
    }
    { const unsigned short* p = xwin(4);
      nx0 = *(const short8*)p; nx1 = *(const short8*)(p + 32); }

    short8 Af0 = 0, Af1 = 0, Af2 = 0, Af3 = 0;

    const unsigned short* haR0 = hflat + (c16 & ~3)*136 + q*8;  // buf0
    const unsigned short* haR1 = haR0 + 2176;                   // buf1
    unsigned short* hw0 = hflat + (4*q)*136 + hu;               // write buf0
    unsigned short* hw1 = hw0 + 2176;                           // write buf1
    unsigned short* hsp = hs + ((size_t)(bt0 + q))*H_ + hu;     // dec hs stores

    // step: R13 core. Global hs stores are fire-and-forget (no vmcnt drain).
    auto step = [&](int t, auto dtc, float4v (&gxP)[4], auto&& pre, auto&& post){
      constexpr int dt = decltype(dtc)::value;
      const unsigned short* ha = (t & 1) ? haR1 : haR0;
      if ((c16 & 3) == dt){            // this step's h-supplier lanes
        Af0 = *(const short8*)(ha);
        Af1 = *(const short8*)(ha + 32);
        Af2 = *(const short8*)(ha + 64);
        Af3 = *(const short8*)(ha + 96);
      }
      pre();

      // K-split chains: aA = gx + kb0 + kb1 ; aB = kb2 + kb3 (from zero).
      float4v aA[4], aB[4];
      #pragma unroll
      for (int g = 0; g < 4; ++g)
        aA[g] = __builtin_amdgcn_mfma_f32_16x16x32_bf16(Af0, Bf[g][0], gxP[g], 0, 0, 0);
      #pragma unroll
      for (int g = 0; g < 4; ++g)
        aB[g] = __builtin_amdgcn_mfma_f32_16x16x32_bf16(Af2, Bf[g][2], z4, 0, 0, 0);
      #pragma unroll
      for (int g = 0; g < 4; ++g)
        aA[g] = __builtin_amdgcn_mfma_f32_16x16x32_bf16(Af1, Bf[g][1], aA[g], 0, 0, 0);
      #pragma unroll
      for (int g = 0; g < 4; ++g)
        aB[g] = __builtin_amdgcn_mfma_f32_16x16x32_bf16(Af3, Bf[g][3], aB[g], 0, 0, 0);

      post();   // safe: C-in (gxP) consumed above

      float gi = aA[0][dt] + aB[0][dt];
      float gf = aA[1][dt] + aB[1][dt];
      float gg = aA[2][dt] + aB[2][dt];
      float go = aA[3][dt] + aB[3][dt];
      float ei  = fexp2(gi * LOG2E);
      float e2g = fexp2(gg * LOG2E2);
      float t1  = (ei * (e2g - 1.0f)) * frcp((1.0f + ei) * (1.0f + e2g));
      float sf  = fsig(gf);
      float c   = fmaf(sf, cst, t1);
      cst = c;
      float eo  = fexp2(go * LOG2E);
      float e2c = fexp2(fminf(c * LOG2E2, 126.0f));
      float h   = (eo * (e2c - 1.0f)) * frcp((1.0f + eo) * (1.0f + e2c));
      unsigned vv;
      asm("v_cvt_pk_bf16_f32 %0, %1, %2" : "=v"(vv) : "v"(h), "v"(zero_f));
      unsigned short hb16 = (unsigned short)vv;
      unsigned short* hw = (t & 1) ? hw0 : hw1;
      hw[0] = hb16;
      if (DEC){ *hsp = hb16; hsp += (size_t)B_*H_; }
      if (!DEC && t == T-1) shT[q][hu] = h;   // enc hT capture (f32, LDS)
      // Raw barrier: drain LDS only; globals stay in flight (R7).
      __builtin_amdgcn_sched_barrier(0);
      asm volatile("s_waitcnt lgkmcnt(0)" ::: "memory");
      __builtin_amdgcn_s_barrier();
      __builtin_amdgcn_sched_barrier(0);
    };

    const int nwin = T >> 2, ntail = T & 3;
    for (int w = 0; w < nwin; ++w){
      const int t0 = w << 2;
      step(t0+0, I0{}, gxA, [&]{
        // gxB = gx(t0+4 .. t0+7); consumes nx loaded 3 steps ago.
        #pragma unroll
        for (int g = 0; g < 4; ++g){
          float4v tt = (float4v){bias[g], bias[g], bias[g], bias[g]};
          tt = __builtin_amdgcn_mfma_f32_16x16x32_bf16(nx0, Bf[g][4], tt, 0, 0, 0);
          gxB[g] = __builtin_amdgcn_mfma_f32_16x16x32_bf16(nx1, Bf[g][5], tt, 0, 0, 0);
        }
      }, nop);
      step(t0+1, I1{}, gxA, [&]{
        // issue loads for window w+2; consumed 3 steps later (dt=0 of w+1).
        const unsigned short* p = xwin(t0 + 8);
        nx0 = *(const short8*)p; nx1 = *(const short8*)(p + 32);
      }, nop);
      step(t0+2, I2{}, gxA, nop, nop);
      step(t0+3, I3{}, gxA, nop, [&]{
        // window rotation AFTER the cluster consumed gxA as C-in
        #pragma unroll
        for (int g = 0; g < 4; ++g) gxA[g] = gxB[g];
      });
    }
    // Tail (dec T=1023: 3 steps). gxA holds gx(nwin*4 ..).
    if (ntail > 0) step(nwin*4+0, I0{}, gxA, nop, nop);
    if (ntail > 1) step(nwin*4+1, I1{}, gxA, nop, nop);
    if (ntail > 2) step(nwin*4+2, I2{}, gxA, nop, nop);
  };

  // ======================= ENCODER =======================
  run(encWih, encWhh, encbih, encbhh, S_, std::integral_constant<bool,false>{});

  // ======================= LATENT (in-WG, 4 batches) =====
  {
    const int bb = tid >> 7, slot = tid & 127;
    const int unit = slot & 63;
    const bool isLv = slot >= 64;
    // mu/lv: per-wave LN over 64 units (wave == (bb,isLv) group exactly)
    const float* W = isLv ? lv_W : mu_W;
    float a = (isLv ? lv_b : mu_b)[unit];
    const float4* wr = (const float4*)(W + unit*H_);
    #pragma unroll 4
    for (int j = 0; j < H_/4; ++j){
      float4 w4 = wr[j];
      a += w4.x*shT[bb][4*j] + w4.y*shT[bb][4*j+1]
         + w4.z*shT[bb][4*j+2] + w4.w*shT[bb][4*j+3];
    }
    a = leaky(a);
    float m = wredsum(a) * (1.0f/L_);
    float d = a - m;
    float v = wredsum(d*d) * (1.0f/L_);
    float y = d * rsqrtf(v + 1e-5f) * (isLv ? lv_g : mu_g)[unit]
            + (isLv ? lv_be : mu_be)[unit];
    out[(isLv ? LV_OFF : MU_OFF) + (size_t)(bt0 + bb)*L_ + unit] = y;
    sml[bb][slot] = y;
    __syncthreads();
    if (!isLv)
      slat[bb][unit] = sml[bb][unit]
                     + eps[(size_t)(bt0 + bb)*L_ + unit] * expf(0.5f*sml[bb][64 + unit]);
    __syncthreads();
    // dh0/dc0: LN over 128 units (waves 2bb / 2bb+1)
    #pragma unroll 1
    for (int which = 0; which < 2; ++which){
      const float* W2 = which ? lc_W : lh_W;
      float p = (which ? lc_b : lh_b)[slot];
      const float4* w2 = (const float4*)(W2 + slot*L_);
      #pragma unroll 4
      for (int j = 0; j < L_/4; ++j){
        float4 w4 = w2[j];
        p += w4.x*slat[bb][4*j] + w4.y*slat[bb][4*j+1]
           + w4.z*slat[bb][4*j+2] + w4.w*slat[bb][4*j+3];
      }
      p = leaky(p);
      float s = wredsum(p);
      if (lane == 0) partA[wave] = s;
      __syncthreads();
      float mean = (partA[2*bb] + partA[2*bb+1]) * (1.0f/H_);
      __syncthreads();
      float dd = p - mean;
      float s2 = wredsum(dd*dd);
      if (lane == 0) partA[wave] = s2;
      __syncthreads();
      float var = (partA[2*bb] + partA[2*bb+1]) * (1.0f/H_);
      __syncthreads();
      float yy = dd * rsqrtf(var + 1e-5f) * (which ? lc_g : lh_g)[slot]
               + (which ? lc_be : lh_be)[slot];
      (which ? sdc : sdh)[bb][slot] = yy;
    }
  }
  __syncthreads();

  // ======================= DECODER (hs stores, free) =====
  run(decWih, decWhh, decbih, decbhh, S_-1, std::integral_constant<bool,true>{});
}

// ---------------- Kernel D: acts/ts heads via MFMA (N=32: 31 acts + ts) -----
__global__ __launch_bounds__(256) void out_kernel(
    const unsigned short* __restrict__ hs,   // [1023][256][128] bf16
    const float* __restrict__ actW, const float* __restrict__ actB,
    const float* __restrict__ timeW, const float* __restrict__ timeB,
    float* __restrict__ out)
{
  const int wave = threadIdx.x >> 6, lane = threadIdx.x & 63;
  const int quad = lane >> 4, c16 = lane & 15;
  const int mt = blockIdx.x * 4 + wave;      // M-tile of 16 rows (r = t*256 + b)
  short8 Wf[2][4]; float biasn[2];
  #pragma unroll
  for (int ti = 0; ti < 2; ++ti){
    const int n = ti*16 + c16;
    biasn[ti] = (n < C_) ? actB[n] : timeB[0];
    #pragma unroll
    for (int kb = 0; kb < 4; ++kb){
      union { short8 v; unsigned short u[8]; } tmp;
      #pragma unroll
      for (int j = 0; j < 8; ++j){
        int k = kb*32 + quad*8 + j;
        tmp.u[j] = f2bf((n < C_) ? actW[n*H_ + k] : timeW[k]);
      }
      Wf[ti][kb] = tmp.v;
    }
  }
  const unsigned short* hp = hs + ((size_t)mt*16 + c16)*H_ + quad*8;
  float4v acc[2];
  #pragma unroll
  for (int ti = 0; ti < 2; ++ti) acc[ti] = (float4v){biasn[ti], biasn[ti], biasn[ti], biasn[ti]};
  #pragma unroll
  for (int kb = 0; kb < 4; ++kb){
    short8 a = *(const short8*)(hp + kb*32);
    acc[0] = __builtin_amdgcn_mfma_f32_16x16x32_bf16(a, Wf[0][kb], acc[0], 0, 0, 0);
    acc[1] = __builtin_amdgcn_mfma_f32_16x16x32_bf16(a, Wf[1][kb], acc[1], 0, 0, 0);
  }
  #pragma unroll
  for (int ti = 0; ti < 2; ++ti){
    const int n = ti*16 + c16;
    #pragma unroll
    for (int r = 0; r < 4; ++r){
      int rr = mt*16 + quad*4 + r;
      int tt = rr >> 8, b = rr & 255;
      float v = acc[ti][r];
      if (n < C_) out[ACTS_OFF + ((size_t)b*1023 + tt)*C_ + n] = v;
      else        out[TS_OFF + (size_t)b*1023 + tt] = v;
    }
  }
}

// ---------------- launch ----------------------------------------------------
extern "C" void kernel_launch(void* const* d_in, const int* in_sizes, int n_in,
                              void* d_out, int out_size, void* d_ws, size_t ws_size,
                              hipStream_t stream)
{
  (void)in_sizes; (void)n_in; (void)out_size; (void)ws_size;
  const float* x       = (const float*)d_in[0];
  const float* eps     = (const float*)d_in[1];
  const float* init_W  = (const float*)d_in[2];
  const float* init_b  = (const float*)d_in[3];
  const float* init_g  = (const float*)d_in[4];
  const float* init_be = (const float*)d_in[5];
  const float* enc_Wih = (const float*)d_in[6];
  const float* enc_Whh = (const float*)d_in[7];
  const float* enc_bih = (const float*)d_in[8];
  const float* enc_bhh = (const float*)d_in[9];
  const float* mu_W  = (const float*)d_in[10];
  const float* mu_b  = (const float*)d_in[11];
  const float* mu_g  = (const float*)d_in[12];
  const float* mu_be = (const float*)d_in[13];
  const float* lv_W  = (const float*)d_in[14];
  const float* lv_b  = (const float*)d_in[15];
  const float* lv_g  = (const float*)d_in[16];
  const float* lv_be = (const float*)d_in[17];
  const float* dec_Wih = (const float*)d_in[18];
  const float* dec_Whh = (const float*)d_in[19];
  const float* dec_bih = (const float*)d_in[20];
  const float* dec_bhh = (const float*)d_in[21];
  const float* lh_W  = (const float*)d_in[22];
  const float* lh_b  = (const float*)d_in[23];
  const float* lh_g  = (const float*)d_in[24];
  const float* lh_be = (const float*)d_in[25];
  const float* lc_W  = (const float*)d_in[26];
  const float* lc_b  = (const float*)d_in[27];
  const float* lc_g  = (const float*)d_in[28];
  const float* lc_be = (const float*)d_in[29];
  const float* act_W  = (const float*)d_in[30];
  const float* act_b  = (const float*)d_in[31];
  const float* time_W = (const float*)d_in[32];
  const float* time_b = (const float*)d_in[33];
  float* out = (float*)d_out;

  // workspace: xemb [1024][256][64] bf16 + 64-short zero pad, hs
  unsigned short* xemb = (unsigned short*)d_ws;
  unsigned short* hs   = xemb + (size_t)S_*B_*E_ + 64;

  init_kernel<<<dim3((B_*S_)/(4*INIT_ROWS)), dim3(256), 0, stream>>>(
      x, init_W, init_b, init_g, init_be, xemb);

  mega_kernel<<<dim3(64), dim3(512), 0, stream>>>(
      xemb,
      enc_Wih, enc_Whh, enc_bih, enc_bhh,
      dec_Wih, dec_Whh, dec_bih, dec_bhh,
      eps,
      mu_W, mu_b, mu_g, mu_be,
      lv_W, lv_b, lv_g, lv_be,
      lh_W, lh_b, lh_g, lh_be,
      lc_W, lc_b, lc_g, lc_be,
      hs, out);

  out_kernel<<<dim3((B_*(S_-1))/16/4), dim3(256), 0, stream>>>(
      hs, act_W, act_b, time_W, time_b, out);
}

// Round 14
// 1156.859 us; speedup vs baseline: 1.1289x; 1.0068x over previous
//
#include <hip/hip_runtime.h>
#include <hip/hip_bf16.h>
#include <type_traits>

// LogVAE. R20 = R19 resubmit (container infra failed twice; no measurement —
//  third infra occurrence this session; R9/R10->R11 and R14->R15 both ran
//  fine on resubmit). Delta vs measured-good R18 re-audited: (1) dropped
//  pre-lgkmcnt sched_barrier — "memory" clobber still orders the ds_write,
//  post-barrier pin kept (rule #18 guard); (2) gxB 4+4 split across dt0/dt2
//  pre-slots with nxN double-buffer rotated at dt=3 (dataflow verified);
//  (3) encoder h_last hoist (uniform control flow).
//  Prediction: mega 990 -> 965-985us; total ~1140-1160us. If flat, declare
//  structural-latency ceiling next round.

#define B_ 256
#define S_ 1024
#define NF_ 32
#define E_ 64
#define H_ 128
#define L_ 64
#define C_ 31

#define ACTS_OFF 0
#define TS_OFF   8118528   // 256*1023*31
#define MU_OFF   8380416   // + 256*1023
#define LV_OFF   8396800   // + 256*64

#define LOG2E  1.44269504f
#define LOG2E2 2.88539008f

typedef __attribute__((ext_vector_type(8))) short short8;
typedef __attribute__((ext_vector_type(4))) float float4v;

__device__ inline unsigned short f2bf(float x){
  union { float f; unsigned u; } a; a.f = x;
  unsigned r = a.u + 0x7FFFu + ((a.u >> 16) & 1u);
  return (unsigned short)(r >> 16);
}
__device__ inline float frcp(float x){
#if __has_builtin(__builtin_amdgcn_rcpf)
  return __builtin_amdgcn_rcpf(x);
#else
  return 1.0f / x;
#endif
}
__device__ inline float fexp2(float x){
#if __has_builtin(__builtin_amdgcn_exp2f)
  return __builtin_amdgcn_exp2f(x);
#else
  return exp2f(x);
#endif
}
__device__ inline float fsig(float x){ return frcp(1.0f + fexp2(-LOG2E*x)); }
__device__ inline float leaky(float x){ return x >= 0.0f ? x : 0.01f*x; }
__device__ inline float wredsum(float v){
  v += __shfl_xor(v, 32, 64);
  v += __shfl_xor(v, 16, 64);
  v += __shfl_xor(v,  8, 64);
  v += __shfl_xor(v,  4, 64);
  v += __shfl_xor(v,  2, 64);
  v += __shfl_xor(v,  1, 64);
  return v;
}

// ---------------- Kernel A: x_emb = LN(leaky(x @ W.T + b)) -> bf16 [S][B][E] --
#define INIT_ROWS 16
__global__ __launch_bounds__(256) void init_kernel(
    const float* __restrict__ x, const float* __restrict__ W,
    const float* __restrict__ bias, const float* __restrict__ gam,
    const float* __restrict__ beta, unsigned short* __restrict__ xemb)
{
  if (blockIdx.x == 0 && threadIdx.x < 64)
    xemb[(size_t)S_*B_*E_ + threadIdx.x] = 0;

  const int wave = threadIdx.x >> 6, lane = threadIdx.x & 63;
  float wf[NF_];
  {
    const float4* wr = (const float4*)(W + lane * NF_);
    #pragma unroll
    for (int j = 0; j < NF_/4; ++j){
      float4 t = wr[j];
      wf[4*j+0] = t.x; wf[4*j+1] = t.y; wf[4*j+2] = t.z; wf[4*j+3] = t.w;
    }
  }
  const float bb = bias[lane], gg = gam[lane], be = beta[lane];

  const int r0 = (blockIdx.x * 4 + wave) * INIT_ROWS;
  for (int rr = 0; rr < INIT_ROWS; ++rr){
    const int ru = __builtin_amdgcn_readfirstlane(r0 + rr);  // wave-uniform row
    const int b = ru >> 10, s = ru & 1023;
    const float* xr = x + (size_t)ru * NF_;   // SGPR-based -> s_loads
    float acc = bb;
    #pragma unroll
    for (int k = 0; k < NF_; ++k)
      acc = fmaf(xr[k], wf[k], acc);
    acc = leaky(acc);
    float m = wredsum(acc) * (1.0f/64.0f);
    float d = acc - m;
    float v = wredsum(d*d) * (1.0f/64.0f);
    float y = d * rsqrtf(v + 1e-5f) * gg + be;
    xemb[((size_t)s * B_ + b) * E_ + lane] = f2bf(y);   // [S][B][E]
  }
}

// ---------------- Megakernel: enc lstm -> latent -> dec lstm -----------------
// grid=64 (4 batch/WG), block=512 (8 waves). lstm core = R13 structure.
__global__ __launch_bounds__(512, 2) void mega_kernel(
    const unsigned short* __restrict__ xemb,  // [S][256][64] bf16 (+64 pad)
    const float* __restrict__ encWih, const float* __restrict__ encWhh,
    const float* __restrict__ encbih, const float* __restrict__ encbhh,
    const float* __restrict__ decWih, const float* __restrict__ decWhh,
    const float* __restrict__ decbih, const float* __restrict__ decbhh,
    const float* __restrict__ eps,
    const float* __restrict__ mu_W, const float* __restrict__ mu_b,
    const float* __restrict__ mu_g, const float* __restrict__ mu_be,
    const float* __restrict__ lv_W, const float* __restrict__ lv_b,
    const float* __restrict__ lv_g, const float* __restrict__ lv_be,
    const float* __restrict__ lh_W, const float* __restrict__ lh_b,
    const float* __restrict__ lh_g, const float* __restrict__ lh_be,
    const float* __restrict__ lc_W, const float* __restrict__ lc_b,
    const float* __restrict__ lc_g, const float* __restrict__ lc_be,
    unsigned short* __restrict__ hs,          // [S-1][256][128] bf16
    float* __restrict__ out)
{
  __shared__ unsigned short hbuf[2][16*136];  // recurrence ping-pong (+8 pad/row)
  __shared__ float shT[4][H_];                // enc hT (f32)
  __shared__ float sml[4][2*L_];              // mu|lv per batch
  __shared__ float slat[4][L_];
  __shared__ float sdh[4][H_], sdc[4][H_];
  __shared__ float partA[8];

  const int tid = threadIdx.x;
  const int wave = tid >> 6, lane = tid & 63;
  const int q = lane >> 4, c16 = lane & 15;
  const int bt0 = blockIdx.x * 4;
  const int hu = wave * 16 + c16;
  unsigned short* hflat = &hbuf[0][0];
  const float4v z4 = (float4v){0.0f, 0.0f, 0.0f, 0.0f};
  float zero_f = 0.0f;

  for (int idx = tid; idx < 2*16*136; idx += 512) hflat[idx] = 0;
  __syncthreads();

  // x window machinery (shared by both phases). Lane A-row = c16 = 4*b + dt.
  const int xb = c16 >> 2, xdt = c16 & 3;
  const unsigned short* xbase = xemb + ((size_t)(bt0 + xb))*E_ + q*8;
  const size_t xrow = (size_t)B_*E_;

  using I0 = std::integral_constant<int,0>;
  using I1 = std::integral_constant<int,1>;
  using I2 = std::integral_constant<int,2>;
  using I3 = std::integral_constant<int,3>;
  auto nop = []{};

  // ================= LSTM runner (enc: DEC=false / dec: DEC=true) ==========
  auto run = [&](const float* Wih, const float* Whh, const float* bih,
                 const float* bhh, int T, auto decc){
    constexpr bool DEC = decltype(decc)::value;

    // Persistent B frags: kb 0..3 = Whh (K=0..128), kb 4..5 = Wih (K=128..192)
    short8 Bf[4][6];
    float bias[4];
    #pragma unroll
    for (int g = 0; g < 4; ++g){
      const int gcol = g*128 + hu;
      bias[g] = bih[gcol] + bhh[gcol];
      #pragma unroll
      for (int kb = 0; kb < 6; ++kb){
        union { short8 v; unsigned short u[8]; } tmp;
        #pragma unroll
        for (int j = 0; j < 8; ++j){
          int k = kb*32 + q*8 + j;
          float wv = (kb < 4) ? Whh[gcol*H_ + k] : Wih[gcol*E_ + (k - H_)];
          tmp.u[j] = f2bf(wv);
        }
        Bf[g][kb] = tmp.v;
      }
    }

    // h0/c0: buf0 rows {0,4,8,12} (other rows stay zero from initial memset)
    {
      int b = tid >> 7, k = tid & 127;   // 512 = 4*128
      hbuf[0][(4*b)*136 + k] = DEC ? f2bf(sdh[b][k]) : (unsigned short)0x3F80;
    }
    float cst = DEC ? sdc[q][hu] : 0.0f;
    __syncthreads();

    auto xwin = [&](int wt)->const unsigned short*{
      int tt = wt + xdt; if (tt > T-1) tt = T-1;   // clamp: garbage rows unused
      return xbase + (size_t)tt * xrow;
    };

    // Prologue: gxA = gx(0..3); nx = x(4..7) in flight.
    float4v gxA[4], gxB[4];
    short8 nx0, nx1, nxN0, nxN1;
    { const unsigned short* p = xwin(0);
      nx0 = *(const short8*)p; nx1 = *(const short8*)(p + 32); }
    #pragma unroll
    for (int g = 0; g < 4; ++g){
      float4v t = (float4v){bias[g], bias[g], bias[g], bias[g]};
      t = __builtin_amdgcn_mfma_f32_16x16x32_bf16(nx0, Bf[g][4], t, 0, 0, 0);
      gxA[g] = __builtin_amdgcn_mfma_f32_16x16x32_bf16(nx1, Bf[g][5], t, 0, 0, 0);
    }
    { const unsigned short* p = xwin(4);
      nx0 = *(const short8*)p; nx1 = *(const short8*)(p + 32); }
    nxN0 = nx0; nxN1 = nx1;

    short8 Af0 = 0, Af1 = 0, Af2 = 0, Af3 = 0;

    const unsigned short* haR0 = hflat + (c16 & ~3)*136 + q*8;  // buf0
    const unsigned short* haR1 = haR0 + 2176;                   // buf1
    unsigned short* hw0 = hflat + (4*q)*136 + hu;               // write buf0
    unsigned short* hw1 = hw0 + 2176;                           // write buf1
    unsigned short* hsp = hs + ((size_t)(bt0 + q))*H_ + hu;     // dec hs stores
    float h_last = 0.0f;                                        // enc hT capture

    // step: R13 core. Global hs stores are fire-and-forget (no vmcnt drain).
    auto step = [&](int t, auto dtc, float4v (&gxP)[4], auto&& pre, auto&& post){
      constexpr int dt = decltype(dtc)::value;
      const unsigned short* ha = (t & 1) ? haR1 : haR0;
      if ((c16 & 3) == dt){            // this step's h-supplier lanes
        Af0 = *(const short8*)(ha);
        Af1 = *(const short8*)(ha + 32);
        Af2 = *(const short8*)(ha + 64);
        Af3 = *(const short8*)(ha + 96);
      }
      pre();

      // K-split chains: aA = gx + kb0 + kb1 ; aB = kb2 + kb3 (from zero).
      float4v aA[4], aB[4];
      #pragma unroll
      for (int g = 0; g < 4; ++g)
        aA[g] = __builtin_amdgcn_mfma_f32_16x16x32_bf16(Af0, Bf[g][0], gxP[g], 0, 0, 0);
      #pragma unroll
      for (int g = 0; g < 4; ++g)
        aB[g] = __builtin_amdgcn_mfma_f32_16x16x32_bf16(Af2, Bf[g][2], z4, 0, 0, 0);
      #pragma unroll
      for (int g = 0; g < 4; ++g)
        aA[g] = __builtin_amdgcn_mfma_f32_16x16x32_bf16(Af1, Bf[g][1], aA[g], 0, 0, 0);
      #pragma unroll
      for (int g = 0; g < 4; ++g)
        aB[g] = __builtin_amdgcn_mfma_f32_16x16x32_bf16(Af3, Bf[g][3], aB[g], 0, 0, 0);

      post();   // safe: C-in (gxP) consumed above

      float gi = aA[0][dt] + aB[0][dt];
      float gf = aA[1][dt] + aB[1][dt];
      float gg = aA[2][dt] + aB[2][dt];
      float go = aA[3][dt] + aB[3][dt];
      float ei  = fexp2(gi * LOG2E);
      float e2g = fexp2(gg * LOG2E2);
      float t1  = (ei * (e2g - 1.0f)) * frcp((1.0f + ei) * (1.0f + e2g));
      float sf  = fsig(gf);
      float c   = fmaf(sf, cst, t1);
      cst = c;
      float eo  = fexp2(go * LOG2E);
      float e2c = fexp2(fminf(c * LOG2E2, 126.0f));
      float h   = (eo * (e2c - 1.0f)) * frcp((1.0f + eo) * (1.0f + e2c));
      unsigned vv;
      asm("v_cvt_pk_bf16_f32 %0, %1, %2" : "=v"(vv) : "v"(h), "v"(zero_f));
      unsigned short hb16 = (unsigned short)vv;
      unsigned short* hw = (t & 1) ? hw0 : hw1;
      hw[0] = hb16;
      if (DEC){ *hsp = hb16; hsp += (size_t)B_*H_; }
      else h_last = h;
      // Raw barrier: drain LDS only; globals stay in flight (R7). Pre-
      // lgkmcnt sched_barrier removed (R19): "memory" clobber orders the
      // ds_write; VALU may sink into the write-drain shadow.
      asm volatile("s_waitcnt lgkmcnt(0)" ::: "memory");
      __builtin_amdgcn_s_barrier();
      __builtin_amdgcn_sched_barrier(0);   // KEEP: no IR fence on s_barrier
    };

    const int nwin = T >> 2, ntail = T & 3;
    for (int w = 0; w < nwin; ++w){
      const int t0 = w << 2;
      step(t0+0, I0{}, gxA, [&]{
        // gxB g=0,1 (consumes nx loaded last window; split with dt=2)
        #pragma unroll
        for (int g = 0; g < 2; ++g){
          float4v tt = (float4v){bias[g], bias[g], bias[g], bias[g]};
          tt = __builtin_amdgcn_mfma_f32_16x16x32_bf16(nx0, Bf[g][4], tt, 0, 0, 0);
          gxB[g] = __builtin_amdgcn_mfma_f32_16x16x32_bf16(nx1, Bf[g][5], tt, 0, 0, 0);
        }
      }, nop);
      step(t0+1, I1{}, gxA, [&]{
        // loads for window w+2 into nxN (nx stays live for dt=2's gxB)
        const unsigned short* p = xwin(t0 + 8);
        nxN0 = *(const short8*)p; nxN1 = *(const short8*)(p + 32);
      }, nop);
      step(t0+2, I2{}, gxA, [&]{
        // gxB g=2,3 (still old nx)
        #pragma unroll
        for (int g = 2; g < 4; ++g){
          float4v tt = (float4v){bias[g], bias[g], bias[g], bias[g]};
          tt = __builtin_amdgcn_mfma_f32_16x16x32_bf16(nx0, Bf[g][4], tt, 0, 0, 0);
          gxB[g] = __builtin_amdgcn_mfma_f32_16x16x32_bf16(nx1, Bf[g][5], tt, 0, 0, 0);
        }
      }, nop);
      step(t0+3, I3{}, gxA, nop, [&]{
        // rotations AFTER consumers: gxA consumed as C-in; nx consumed at dt=2
        #pragma unroll
        for (int g = 0; g < 4; ++g) gxA[g] = gxB[g];
        nx0 = nxN0; nx1 = nxN1;
      });
    }
    // Tail (dec T=1023: 3 steps). gxA holds gx(nwin*4 ..).
    if (ntail > 0) step(nwin*4+0, I0{}, gxA, nop, nop);
    if (ntail > 1) step(nwin*4+1, I1{}, gxA, nop, nop);
    if (ntail > 2) step(nwin*4+2, I2{}, gxA, nop, nop);

    if (!DEC){ shT[q][hu] = h_last; __syncthreads(); }  // hT for latent
  };

  // ======================= ENCODER =======================
  run(encWih, encWhh, encbih, encbhh, S_, std::integral_constant<bool,false>{});

  // ======================= LATENT (in-WG, 4 batches) =====
  {
    const int bb = tid >> 7, slot = tid & 127;
    const int unit = slot & 63;
    const bool isLv = slot >= 64;
    // mu/lv: per-wave LN over 64 units (wave == (bb,isLv) group exactly)
    const float* W = isLv ? lv_W : mu_W;
    float a = (isLv ? lv_b : mu_b)[unit];
    const float4* wr = (const float4*)(W + unit*H_);
    #pragma unroll 4
    for (int j = 0; j < H_/4; ++j){
      float4 w4 = wr[j];
      a += w4.x*shT[bb][4*j] + w4.y*shT[bb][4*j+1]
         + w4.z*shT[bb][4*j+2] + w4.w*shT[bb][4*j+3];
    }
    a = leaky(a);
    float m = wredsum(a) * (1.0f/L_);
    float d = a - m;
    float v = wredsum(d*d) * (1.0f/L_);
    float y = d * rsqrtf(v + 1e-5f) * (isLv ? lv_g : mu_g)[unit]
            + (isLv ? lv_be : mu_be)[unit];
    out[(isLv ? LV_OFF : MU_OFF) + (size_t)(bt0 + bb)*L_ + unit] = y;
    sml[bb][slot] = y;
    __syncthreads();
    if (!isLv)
      slat[bb][unit] = sml[bb][unit]
                     + eps[(size_t)(bt0 + bb)*L_ + unit] * expf(0.5f*sml[bb][64 + unit]);
    __syncthreads();
    // dh0/dc0: LN over 128 units (waves 2bb / 2bb+1)
    #pragma unroll 1
    for (int which = 0; which < 2; ++which){
      const float* W2 = which ? lc_W : lh_W;
      float p = (which ? lc_b : lh_b)[slot];
      const float4* w2 = (const float4*)(W2 + slot*L_);
      #pragma unroll 4
      for (int j = 0; j < L_/4; ++j){
        float4 w4 = w2[j];
        p += w4.x*slat[bb][4*j] + w4.y*slat[bb][4*j+1]
           + w4.z*slat[bb][4*j+2] + w4.w*slat[bb][4*j+3];
      }
      p = leaky(p);
      float s = wredsum(p);
      if (lane == 0) partA[wave] = s;
      __syncthreads();
      float mean = (partA[2*bb] + partA[2*bb+1]) * (1.0f/H_);
      __syncthreads();
      float dd = p - mean;
      float s2 = wredsum(dd*dd);
      if (lane == 0) partA[wave] = s2;
      __syncthreads();
      float var = (partA[2*bb] + partA[2*bb+1]) * (1.0f/H_);
      __syncthreads();
      float yy = dd * rsqrtf(var + 1e-5f) * (which ? lc_g : lh_g)[slot]
               + (which ? lc_be : lh_be)[slot];
      (which ? sdc : sdh)[bb][slot] = yy;
    }
  }
  __syncthreads();

  // ======================= DECODER (hs stores, free) =====
  run(decWih, decWhh, decbih, decbhh, S_-1, std::integral_constant<bool,true>{});
}

// ---------------- Kernel D: acts/ts heads via MFMA (N=32: 31 acts + ts) -----
__global__ __launch_bounds__(256) void out_kernel(
    const unsigned short* __restrict__ hs,   // [1023][256][128] bf16
    const float* __restrict__ actW, const float* __restrict__ actB,
    const float* __restrict__ timeW, const float* __restrict__ timeB,
    float* __restrict__ out)
{
  const int wave = threadIdx.x >> 6, lane = threadIdx.x & 63;
  const int quad = lane >> 4, c16 = lane & 15;
  const int mt = blockIdx.x * 4 + wave;      // M-tile of 16 rows (r = t*256 + b)
  short8 Wf[2][4]; float biasn[2];
  #pragma unroll
  for (int ti = 0; ti < 2; ++ti){
    const int n = ti*16 + c16;
    biasn[ti] = (n < C_) ? actB[n] : timeB[0];
    #pragma unroll
    for (int kb = 0; kb < 4; ++kb){
      union { short8 v; unsigned short u[8]; } tmp;
      #pragma unroll
      for (int j = 0; j < 8; ++j){
        int k = kb*32 + quad*8 + j;
        tmp.u[j] = f2bf((n < C_) ? actW[n*H_ + k] : timeW[k]);
      }
      Wf[ti][kb] = tmp.v;
    }
  }
  const unsigned short* hp = hs + ((size_t)mt*16 + c16)*H_ + quad*8;
  float4v acc[2];
  #pragma unroll
  for (int ti = 0; ti < 2; ++ti) acc[ti] = (float4v){biasn[ti], biasn[ti], biasn[ti], biasn[ti]};
  #pragma unroll
  for (int kb = 0; kb < 4; ++kb){
    short8 a = *(const short8*)(hp + kb*32);
    acc[0] = __builtin_amdgcn_mfma_f32_16x16x32_bf16(a, Wf[0][kb], acc[0], 0, 0, 0);
    acc[1] = __builtin_amdgcn_mfma_f32_16x16x32_bf16(a, Wf[1][kb], acc[1], 0, 0, 0);
  }
  #pragma unroll
  for (int ti = 0; ti < 2; ++ti){
    const int n = ti*16 + c16;
    #pragma unroll
    for (int r = 0; r < 4; ++r){
      int rr = mt*16 + quad*4 + r;
      int tt = rr >> 8, b = rr & 255;
      float v = acc[ti][r];
      if (n < C_) out[ACTS_OFF + ((size_t)b*1023 + tt)*C_ + n] = v;
      else        out[TS_OFF + (size_t)b*1023 + tt] = v;
    }
  }
}

// ---------------- launch ----------------------------------------------------
extern "C" void kernel_launch(void* const* d_in, const int* in_sizes, int n_in,
                              void* d_out, int out_size, void* d_ws, size_t ws_size,
                              hipStream_t stream)
{
  (void)in_sizes; (void)n_in; (void)out_size; (void)ws_size;
  const float* x       = (const float*)d_in[0];
  const float* eps     = (const float*)d_in[1];
  const float* init_W  = (const float*)d_in[2];
  const float* init_b  = (const float*)d_in[3];
  const float* init_g  = (const float*)d_in[4];
  const float* init_be = (const float*)d_in[5];
  const float* enc_Wih = (const float*)d_in[6];
  const float* enc_Whh = (const float*)d_in[7];
  const float* enc_bih = (const float*)d_in[8];
  const float* enc_bhh = (const float*)d_in[9];
  const float* mu_W  = (const float*)d_in[10];
  const float* mu_b  = (const float*)d_in[11];
  const float* mu_g  = (const float*)d_in[12];
  const float* mu_be = (const float*)d_in[13];
  const float* lv_W  = (const float*)d_in[14];
  const float* lv_b  = (const float*)d_in[15];
  const float* lv_g  = (const float*)d_in[16];
  const float* lv_be = (const float*)d_in[17];
  const float* dec_Wih = (const float*)d_in[18];
  const float* dec_Whh = (const float*)d_in[19];
  const float* dec_bih = (const float*)d_in[20];
  const float* dec_bhh = (const float*)d_in[21];
  const float* lh_W  = (const float*)d_in[22];
  const float* lh_b  = (const float*)d_in[23];
  const float* lh_g  = (const float*)d_in[24];
  const float* lh_be = (const float*)d_in[25];
  const float* lc_W  = (const float*)d_in[26];
  const float* lc_b  = (const float*)d_in[27];
  const float* lc_g  = (const float*)d_in[28];
  const float* lc_be = (const float*)d_in[29];
  const float* act_W  = (const float*)d_in[30];
  const float* act_b  = (const float*)d_in[31];
  const float* time_W = (const float*)d_in[32];
  const float* time_b = (const float*)d_in[33];
  float* out = (float*)d_out;

  // workspace: xemb [1024][256][64] bf16 + 64-short zero pad, hs
  unsigned short* xemb = (unsigned short*)d_ws;
  unsigned short* hs   = xemb + (size_t)S_*B_*E_ + 64;

  init_kernel<<<dim3((B_*S_)/(4*INIT_ROWS)), dim3(256), 0, stream>>>(
      x, init_W, init_b, init_g, init_be, xemb);

  mega_kernel<<<dim3(64), dim3(512), 0, stream>>>(
      xemb,
      enc_Wih, enc_Whh, enc_bih, enc_bhh,
      dec_Wih, dec_Whh, dec_bih, dec_bhh,
      eps,
      mu_W, mu_b, mu_g, mu_be,
      lv_W, lv_b, lv_g, lv_be,
      lh_W, lh_b, lh_g, lh_be,
      lc_W, lc_b, lc_g, lc_be,
      hs, out);

  out_kernel<<<dim3((B_*(S_-1))/16/4), dim3(256), 0, stream>>>(
      hs, act_W, act_b, time_W, time_b, out);
}

// Round 15
// 1134.672 us; speedup vs baseline: 1.1509x; 1.0196x over previous
//
#include <hip/hip_runtime.h>
#include <hip/hip_bf16.h>
#include <type_traits>

// LogVAE. R21 (from R20 @1156.9us best; mega 974 = enc 487 + lat 5 + dec 487).
//  Step-loop issue shaving: per-step SIMD issue ~500cy of ~1142cy step; each
//  removed wave-instruction saves ~2cy/step.
//  (1) 2-WINDOW ROLE PING-PONG: unroll window pairs with (gxA,gxB,nx,nxN)
//      then (gxB,gxA,nxN,nx) as (cur,next) refs — compile-time binding,
//      kills 24 rotation v_movs/window/wave (16 gx + 8 nx).
//  (2) gxNext spread 2+2+2+2 across all 4 dt pre-slots (was 4+4 at dt0/dt2);
//      each gxNext[g] produced >=4 steps before consumption.
//  Odd-nwin tail (dec: 255) runs one unpaired window, tail reads gxB;
//  even (enc: 256) reads gxA. Everything else = R20.
//  Stop rule: gain <8us -> declare structural-latency ceiling next round.

#define B_ 256
#define S_ 1024
#define NF_ 32
#define E_ 64
#define H_ 128
#define L_ 64
#define C_ 31

#define ACTS_OFF 0
#define TS_OFF   8118528   // 256*1023*31
#define MU_OFF   8380416   // + 256*1023
#define LV_OFF   8396800   // + 256*64

#define LOG2E  1.44269504f
#define LOG2E2 2.88539008f

typedef __attribute__((ext_vector_type(8))) short short8;
typedef __attribute__((ext_vector_type(4))) float float4v;

__device__ inline unsigned short f2bf(float x){
  union { float f; unsigned u; } a; a.f = x;
  unsigned r = a.u + 0x7FFFu + ((a.u >> 16) & 1u);
  return (unsigned short)(r >> 16);
}
__device__ inline float frcp(float x){
#if __has_builtin(__builtin_amdgcn_rcpf)
  return __builtin_amdgcn_rcpf(x);
#else
  return 1.0f / x;
#endif
}
__device__ inline float fexp2(float x){
#if __has_builtin(__builtin_amdgcn_exp2f)
  return __builtin_amdgcn_exp2f(x);
#else
  return exp2f(x);
#endif
}
__device__ inline float fsig(float x){ return frcp(1.0f + fexp2(-LOG2E*x)); }
__device__ inline float leaky(float x){ return x >= 0.0f ? x : 0.01f*x; }
__device__ inline float wredsum(float v){
  v += __shfl_xor(v, 32, 64);
  v += __shfl_xor(v, 16, 64);
  v += __shfl_xor(v,  8, 64);
  v += __shfl_xor(v,  4, 64);
  v += __shfl_xor(v,  2, 64);
  v += __shfl_xor(v,  1, 64);
  return v;
}

// ---------------- Kernel A: x_emb = LN(leaky(x @ W.T + b)) -> bf16 [S][B][E] --
#define INIT_ROWS 16
__global__ __launch_bounds__(256) void init_kernel(
    const float* __restrict__ x, const float* __restrict__ W,
    const float* __restrict__ bias, const float* __restrict__ gam,
    const float* __restrict__ beta, unsigned short* __restrict__ xemb)
{
  if (blockIdx.x == 0 && threadIdx.x < 64)
    xemb[(size_t)S_*B_*E_ + threadIdx.x] = 0;

  const int wave = threadIdx.x >> 6, lane = threadIdx.x & 63;
  float wf[NF_];
  {
    const float4* wr = (const float4*)(W + lane * NF_);
    #pragma unroll
    for (int j = 0; j < NF_/4; ++j){
      float4 t = wr[j];
      wf[4*j+0] = t.x; wf[4*j+1] = t.y; wf[4*j+2] = t.z; wf[4*j+3] = t.w;
    }
  }
  const float bb = bias[lane], gg = gam[lane], be = beta[lane];

  const int r0 = (blockIdx.x * 4 + wave) * INIT_ROWS;
  for (int rr = 0; rr < INIT_ROWS; ++rr){
    const int ru = __builtin_amdgcn_readfirstlane(r0 + rr);  // wave-uniform row
    const int b = ru >> 10, s = ru & 1023;
    const float* xr = x + (size_t)ru * NF_;   // SGPR-based -> s_loads
    float acc = bb;
    #pragma unroll
    for (int k = 0; k < NF_; ++k)
      acc = fmaf(xr[k], wf[k], acc);
    acc = leaky(acc);
    float m = wredsum(acc) * (1.0f/64.0f);
    float d = acc - m;
    float v = wredsum(d*d) * (1.0f/64.0f);
    float y = d * rsqrtf(v + 1e-5f) * gg + be;
    xemb[((size_t)s * B_ + b) * E_ + lane] = f2bf(y);   // [S][B][E]
  }
}

// ---------------- Megakernel: enc lstm -> latent -> dec lstm -----------------
// grid=64 (4 batch/WG), block=512 (8 waves). lstm core = R13 structure.
__global__ __launch_bounds__(512, 2) void mega_kernel(
    const unsigned short* __restrict__ xemb,  // [S][256][64] bf16 (+64 pad)
    const float* __restrict__ encWih, const float* __restrict__ encWhh,
    const float* __restrict__ encbih, const float* __restrict__ encbhh,
    const float* __restrict__ decWih, const float* __restrict__ decWhh,
    const float* __restrict__ decbih, const float* __restrict__ decbhh,
    const float* __restrict__ eps,
    const float* __restrict__ mu_W, const float* __restrict__ mu_b,
    const float* __restrict__ mu_g, const float* __restrict__ mu_be,
    const float* __restrict__ lv_W, const float* __restrict__ lv_b,
    const float* __restrict__ lv_g, const float* __restrict__ lv_be,
    const float* __restrict__ lh_W, const float* __restrict__ lh_b,
    const float* __restrict__ lh_g, const float* __restrict__ lh_be,
    const float* __restrict__ lc_W, const float* __restrict__ lc_b,
    const float* __restrict__ lc_g, const float* __restrict__ lc_be,
    unsigned short* __restrict__ hs,          // [S-1][256][128] bf16
    float* __restrict__ out)
{
  __shared__ unsigned short hbuf[2][16*136];  // recurrence ping-pong (+8 pad/row)
  __shared__ float shT[4][H_];                // enc hT (f32)
  __shared__ float sml[4][2*L_];              // mu|lv per batch
  __shared__ float slat[4][L_];
  __shared__ float sdh[4][H_], sdc[4][H_];
  __shared__ float partA[8];

  const int tid = threadIdx.x;
  const int wave = tid >> 6, lane = tid & 63;
  const int q = lane >> 4, c16 = lane & 15;
  const int bt0 = blockIdx.x * 4;
  const int hu = wave * 16 + c16;
  unsigned short* hflat = &hbuf[0][0];
  const float4v z4 = (float4v){0.0f, 0.0f, 0.0f, 0.0f};
  float zero_f = 0.0f;

  for (int idx = tid; idx < 2*16*136; idx += 512) hflat[idx] = 0;
  __syncthreads();

  // x window machinery (shared by both phases). Lane A-row = c16 = 4*b + dt.
  const int xb = c16 >> 2, xdt = c16 & 3;
  const unsigned short* xbase = xemb + ((size_t)(bt0 + xb))*E_ + q*8;
  const size_t xrow = (size_t)B_*E_;

  using I0 = std::integral_constant<int,0>;
  using I1 = std::integral_constant<int,1>;
  using I2 = std::integral_constant<int,2>;
  using I3 = std::integral_constant<int,3>;
  auto nop = []{};

  // ================= LSTM runner (enc: DEC=false / dec: DEC=true) ==========
  auto run = [&](const float* Wih, const float* Whh, const float* bih,
                 const float* bhh, int T, auto decc){
    constexpr bool DEC = decltype(decc)::value;

    // Persistent B frags: kb 0..3 = Whh (K=0..128), kb 4..5 = Wih (K=128..192)
    short8 Bf[4][6];
    float bias[4];
    #pragma unroll
    for (int g = 0; g < 4; ++g){
      const int gcol = g*128 + hu;
      bias[g] = bih[gcol] + bhh[gcol];
      #pragma unroll
      for (int kb = 0; kb < 6; ++kb){
        union { short8 v; unsigned short u[8]; } tmp;
        #pragma unroll
        for (int j = 0; j < 8; ++j){
          int k = kb*32 + q*8 + j;
          float wv = (kb < 4) ? Whh[gcol*H_ + k] : Wih[gcol*E_ + (k - H_)];
          tmp.u[j] = f2bf(wv);
        }
        Bf[g][kb] = tmp.v;
      }
    }

    // h0/c0: buf0 rows {0,4,8,12} (other rows stay zero from initial memset)
    {
      int b = tid >> 7, k = tid & 127;   // 512 = 4*128
      hbuf[0][(4*b)*136 + k] = DEC ? f2bf(sdh[b][k]) : (unsigned short)0x3F80;
    }
    float cst = DEC ? sdc[q][hu] : 0.0f;
    __syncthreads();

    auto xwin = [&](int wt)->const unsigned short*{
      int tt = wt + xdt; if (tt > T-1) tt = T-1;   // clamp: garbage rows unused
      return xbase + (size_t)tt * xrow;
    };

    // Prologue: gxA = gx(0..3); nx = x(4..7) in flight.
    float4v gxA[4], gxB[4];
    short8 nx0, nx1, nxN0, nxN1;
    { const unsigned short* p = xwin(0);
      nx0 = *(const short8*)p; nx1 = *(const short8*)(p + 32); }
    #pragma unroll
    for (int g = 0; g < 4; ++g){
      float4v t = (float4v){bias[g], bias[g], bias[g], bias[g]};
      t = __builtin_amdgcn_mfma_f32_16x16x32_bf16(nx0, Bf[g][4], t, 0, 0, 0);
      gxA[g] = __builtin_amdgcn_mfma_f32_16x16x32_bf16(nx1, Bf[g][5], t, 0, 0, 0);
    }
    { const unsigned short* p = xwin(4);
      nx0 = *(const short8*)p; nx1 = *(const short8*)(p + 32); }
    nxN0 = nx0; nxN1 = nx1;   // defined-init; overwritten by window 0's dt1

    short8 Af0 = 0, Af1 = 0, Af2 = 0, Af3 = 0;

    const unsigned short* haR0 = hflat + (c16 & ~3)*136 + q*8;  // buf0
    const unsigned short* haR1 = haR0 + 2176;                   // buf1
    unsigned short* hw0 = hflat + (4*q)*136 + hu;               // write buf0
    unsigned short* hw1 = hw0 + 2176;                           // write buf1
    unsigned short* hsp = hs + ((size_t)(bt0 + q))*H_ + hu;     // dec hs stores
    float h_last = 0.0f;                                        // enc hT capture

    // step: R13 core. Global hs stores are fire-and-forget (no vmcnt drain).
    auto step = [&](int t, auto dtc, float4v (&gxP)[4], auto&& pre){
      constexpr int dt = decltype(dtc)::value;
      const unsigned short* ha = (t & 1) ? haR1 : haR0;
      if ((c16 & 3) == dt){            // this step's h-supplier lanes
        Af0 = *(const short8*)(ha);
        Af1 = *(const short8*)(ha + 32);
        Af2 = *(const short8*)(ha + 64);
        Af3 = *(const short8*)(ha + 96);
      }
      pre();

      // K-split chains: aA = gx + kb0 + kb1 ; aB = kb2 + kb3 (from zero).
      float4v aA[4], aB[4];
      #pragma unroll
      for (int g = 0; g < 4; ++g)
        aA[g] = __builtin_amdgcn_mfma_f32_16x16x32_bf16(Af0, Bf[g][0], gxP[g], 0, 0, 0);
      #pragma unroll
      for (int g = 0; g < 4; ++g)
        aB[g] = __builtin_amdgcn_mfma_f32_16x16x32_bf16(Af2, Bf[g][2], z4, 0, 0, 0);
      #pragma unroll
      for (int g = 0; g < 4; ++g)
        aA[g] = __builtin_amdgcn_mfma_f32_16x16x32_bf16(Af1, Bf[g][1], aA[g], 0, 0, 0);
      #pragma unroll
      for (int g = 0; g < 4; ++g)
        aB[g] = __builtin_amdgcn_mfma_f32_16x16x32_bf16(Af3, Bf[g][3], aB[g], 0, 0, 0);

      float gi = aA[0][dt] + aB[0][dt];
      float gf = aA[1][dt] + aB[1][dt];
      float gg = aA[2][dt] + aB[2][dt];
      float go = aA[3][dt] + aB[3][dt];
      float ei  = fexp2(gi * LOG2E);
      float e2g = fexp2(gg * LOG2E2);
      float t1  = (ei * (e2g - 1.0f)) * frcp((1.0f + ei) * (1.0f + e2g));
      float sf  = fsig(gf);
      float c   = fmaf(sf, cst, t1);
      cst = c;
      float eo  = fexp2(go * LOG2E);
      float e2c = fexp2(fminf(c * LOG2E2, 126.0f));
      float h   = (eo * (e2c - 1.0f)) * frcp((1.0f + eo) * (1.0f + e2c));
      unsigned vv;
      asm("v_cvt_pk_bf16_f32 %0, %1, %2" : "=v"(vv) : "v"(h), "v"(zero_f));
      unsigned short hb16 = (unsigned short)vv;
      unsigned short* hw = (t & 1) ? hw0 : hw1;
      hw[0] = hb16;
      if (DEC){ *hsp = hb16; hsp += (size_t)B_*H_; }
      else h_last = h;
      // Raw barrier: drain LDS only; globals stay in flight (R7). Pre-
      // lgkmcnt sched_barrier removed (R19): "memory" clobber orders the
      // ds_write; VALU may sink into the write-drain shadow.
      asm volatile("s_waitcnt lgkmcnt(0)" ::: "memory");
      __builtin_amdgcn_s_barrier();
      __builtin_amdgcn_sched_barrier(0);   // KEEP: no IR fence on s_barrier
    };

    // window: 4 steps consuming gxCur; builds gxNxt (2 MFMAs per dt slot)
    // from nxc (= x(t0+4..t0+7)); loads x(t0+8..t0+11) into nxn at dt1.
    // Role ping-pong across windows: zero rotation movs (R21).
    auto window = [&](int t0, float4v (&gxCur)[4], float4v (&gxNxt)[4],
                      short8& nxc0, short8& nxc1, short8& nxn0, short8& nxn1){
      step(t0+0, I0{}, gxCur, [&]{
        float4v tt = (float4v){bias[0], bias[0], bias[0], bias[0]};
        tt = __builtin_amdgcn_mfma_f32_16x16x32_bf16(nxc0, Bf[0][4], tt, 0, 0, 0);
        gxNxt[0] = __builtin_amdgcn_mfma_f32_16x16x32_bf16(nxc1, Bf[0][5], tt, 0, 0, 0);
      });
      step(t0+1, I1{}, gxCur, [&]{
        const unsigned short* p = xwin(t0 + 8);
        nxn0 = *(const short8*)p; nxn1 = *(const short8*)(p + 32);
        float4v tt = (float4v){bias[1], bias[1], bias[1], bias[1]};
        tt = __builtin_amdgcn_mfma_f32_16x16x32_bf16(nxc0, Bf[1][4], tt, 0, 0, 0);
        gxNxt[1] = __builtin_amdgcn_mfma_f32_16x16x32_bf16(nxc1, Bf[1][5], tt, 0, 0, 0);
      });
      step(t0+2, I2{}, gxCur, [&]{
        float4v tt = (float4v){bias[2], bias[2], bias[2], bias[2]};
        tt = __builtin_amdgcn_mfma_f32_16x16x32_bf16(nxc0, Bf[2][4], tt, 0, 0, 0);
        gxNxt[2] = __builtin_amdgcn_mfma_f32_16x16x32_bf16(nxc1, Bf[2][5], tt, 0, 0, 0);
      });
      step(t0+3, I3{}, gxCur, [&]{
        float4v tt = (float4v){bias[3], bias[3], bias[3], bias[3]};
        tt = __builtin_amdgcn_mfma_f32_16x16x32_bf16(nxc0, Bf[3][4], tt, 0, 0, 0);
        gxNxt[3] = __builtin_amdgcn_mfma_f32_16x16x32_bf16(nxc1, Bf[3][5], tt, 0, 0, 0);
      });
    };

    const int nwin = T >> 2, ntail = T & 3;
    int w = 0;
    for (; w + 2 <= nwin; w += 2){
      window((w    ) << 2, gxA, gxB, nx0,  nx1,  nxN0, nxN1);
      window((w + 1) << 2, gxB, gxA, nxN0, nxN1, nx0,  nx1);
    }
    if (w < nwin){   // odd nwin (dec: 255): unpaired window; tail reads gxB
      window(w << 2, gxA, gxB, nx0, nx1, nxN0, nxN1);
      if (ntail > 0) step(nwin*4+0, I0{}, gxB, nop);
      if (ntail > 1) step(nwin*4+1, I1{}, gxB, nop);
      if (ntail > 2) step(nwin*4+2, I2{}, gxB, nop);
    } else {         // even nwin (enc: 256): tail reads gxA
      if (ntail > 0) step(nwin*4+0, I0{}, gxA, nop);
      if (ntail > 1) step(nwin*4+1, I1{}, gxA, nop);
      if (ntail > 2) step(nwin*4+2, I2{}, gxA, nop);
    }

    if (!DEC){ shT[q][hu] = h_last; __syncthreads(); }  // hT for latent
  };

  // ======================= ENCODER =======================
  run(encWih, encWhh, encbih, encbhh, S_, std::integral_constant<bool,false>{});

  // ======================= LATENT (in-WG, 4 batches) =====
  {
    const int bb = tid >> 7, slot = tid & 127;
    const int unit = slot & 63;
    const bool isLv = slot >= 64;
    // mu/lv: per-wave LN over 64 units (wave == (bb,isLv) group exactly)
    const float* W = isLv ? lv_W : mu_W;
    float a = (isLv ? lv_b : mu_b)[unit];
    const float4* wr = (const float4*)(W + unit*H_);
    #pragma unroll 4
    for (int j = 0; j < H_/4; ++j){
      float4 w4 = wr[j];
      a += w4.x*shT[bb][4*j] + w4.y*shT[bb][4*j+1]
         + w4.z*shT[bb][4*j+2] + w4.w*shT[bb][4*j+3];
    }
    a = leaky(a);
    float m = wredsum(a) * (1.0f/L_);
    float d = a - m;
    float v = wredsum(d*d) * (1.0f/L_);
    float y = d * rsqrtf(v + 1e-5f) * (isLv ? lv_g : mu_g)[unit]
            + (isLv ? lv_be : mu_be)[unit];
    out[(isLv ? LV_OFF : MU_OFF) + (size_t)(bt0 + bb)*L_ + unit] = y;
    sml[bb][slot] = y;
    __syncthreads();
    if (!isLv)
      slat[bb][unit] = sml[bb][unit]
                     + eps[(size_t)(bt0 + bb)*L_ + unit] * expf(0.5f*sml[bb][64 + unit]);
    __syncthreads();
    // dh0/dc0: LN over 128 units (waves 2bb / 2bb+1)
    #pragma unroll 1
    for (int which = 0; which < 2; ++which){
      const float* W2 = which ? lc_W : lh_W;
      float p = (which ? lc_b : lh_b)[slot];
      const float4* w2 = (const float4*)(W2 + slot*L_);
      #pragma unroll 4
      for (int j = 0; j < L_/4; ++j){
        float4 w4 = w2[j];
        p += w4.x*slat[bb][4*j] + w4.y*slat[bb][4*j+1]
           + w4.z*slat[bb][4*j+2] + w4.w*slat[bb][4*j+3];
      }
      p = leaky(p);
      float s = wredsum(p);
      if (lane == 0) partA[wave] = s;
      __syncthreads();
      float mean = (partA[2*bb] + partA[2*bb+1]) * (1.0f/H_);
      __syncthreads();
      float dd = p - mean;
      float s2 = wredsum(dd*dd);
      if (lane == 0) partA[wave] = s2;
      __syncthreads();
      float var = (partA[2*bb] + partA[2*bb+1]) * (1.0f/H_);
      __syncthreads();
      float yy = dd * rsqrtf(var + 1e-5f) * (which ? lc_g : lh_g)[slot]
               + (which ? lc_be : lh_be)[slot];
      (which ? sdc : sdh)[bb][slot] = yy;
    }
  }
  __syncthreads();

  // ======================= DECODER (hs stores, free) =====
  run(decWih, decWhh, decbih, decbhh, S_-1, std::integral_constant<bool,true>{});
}

// ---------------- Kernel D: acts/ts heads via MFMA (N=32: 31 acts + ts) -----
__global__ __launch_bounds__(256) void out_kernel(
    const unsigned short* __restrict__ hs,   // [1023][256][128] bf16
    const float* __restrict__ actW, const float* __restrict__ actB,
    const float* __restrict__ timeW, const float* __restrict__ timeB,
    float* __restrict__ out)
{
  const int wave = threadIdx.x >> 6, lane = threadIdx.x & 63;
  const int quad = lane >> 4, c16 = lane & 15;
  const int mt = blockIdx.x * 4 + wave;      // M-tile of 16 rows (r = t*256 + b)
  short8 Wf[2][4]; float biasn[2];
  #pragma unroll
  for (int ti = 0; ti < 2; ++ti){
    const int n = ti*16 + c16;
    biasn[ti] = (n < C_) ? actB[n] : timeB[0];
    #pragma unroll
    for (int kb = 0; kb < 4; ++kb){
      union { short8 v; unsigned short u[8]; } tmp;
      #pragma unroll
      for (int j = 0; j < 8; ++j){
        int k = kb*32 + quad*8 + j;
        tmp.u[j] = f2bf((n < C_) ? actW[n*H_ + k] : timeW[k]);
      }
      Wf[ti][kb] = tmp.v;
    }
  }
  const unsigned short* hp = hs + ((size_t)mt*16 + c16)*H_ + quad*8;
  float4v acc[2];
  #pragma unroll
  for (int ti = 0; ti < 2; ++ti) acc[ti] = (float4v){biasn[ti], biasn[ti], biasn[ti], biasn[ti]};
  #pragma unroll
  for (int kb = 0; kb < 4; ++kb){
    short8 a = *(const short8*)(hp + kb*32);
    acc[0] = __builtin_amdgcn_mfma_f32_16x16x32_bf16(a, Wf[0][kb], acc[0], 0, 0, 0);
    acc[1] = __builtin_amdgcn_mfma_f32_16x16x32_bf16(a, Wf[1][kb], acc[1], 0, 0, 0);
  }
  #pragma unroll
  for (int ti = 0; ti < 2; ++ti){
    const int n = ti*16 + c16;
    #pragma unroll
    for (int r = 0; r < 4; ++r){
      int rr = mt*16 + quad*4 + r;
      int tt = rr >> 8, b = rr & 255;
      float v = acc[ti][r];
      if (n < C_) out[ACTS_OFF + ((size_t)b*1023 + tt)*C_ + n] = v;
      else        out[TS_OFF + (size_t)b*1023 + tt] = v;
    }
  }
}

// ---------------- launch ----------------------------------------------------
extern "C" void kernel_launch(void* const* d_in, const int* in_sizes, int n_in,
                              void* d_out, int out_size, void* d_ws, size_t ws_size,
                              hipStream_t stream)
{
  (void)in_sizes; (void)n_in; (void)out_size; (void)ws_size;
  const float* x       = (const float*)d_in[0];
  const float* eps     = (const float*)d_in[1];
  const float* init_W  = (const float*)d_in[2];
  const float* init_b  = (const float*)d_in[3];
  const float* init_g  = (const float*)d_in[4];
  const float* init_be = (const float*)d_in[5];
  const float* enc_Wih = (const float*)d_in[6];
  const float* enc_Whh = (const float*)d_in[7];
  const float* enc_bih = (const float*)d_in[8];
  const float* enc_bhh = (const float*)d_in[9];
  const float* mu_W  = (const float*)d_in[10];
  const float* mu_b  = (const float*)d_in[11];
  const float* mu_g  = (const float*)d_in[12];
  const float* mu_be = (const float*)d_in[13];
  const float* lv_W  = (const float*)d_in[14];
  const float* lv_b  = (const float*)d_in[15];
  const float* lv_g  = (const float*)d_in[16];
  const float* lv_be = (const float*)d_in[17];
  const float* dec_Wih = (const float*)d_in[18];
  const float* dec_Whh = (const float*)d_in[19];
  const float* dec_bih = (const float*)d_in[20];
  const float* dec_bhh = (const float*)d_in[21];
  const float* lh_W  = (const float*)d_in[22];
  const float* lh_b  = (const float*)d_in[23];
  const float* lh_g  = (const float*)d_in[24];
  const float* lh_be = (const float*)d_in[25];
  const float* lc_W  = (const float*)d_in[26];
  const float* lc_b  = (const float*)d_in[27];
  const float* lc_g  = (const float*)d_in[28];
  const float* lc_be = (const float*)d_in[29];
  const float* act_W  = (const float*)d_in[30];
  const float* act_b  = (const float*)d_in[31];
  const float* time_W = (const float*)d_in[32];
  const float* time_b = (const float*)d_in[33];
  float* out = (float*)d_out;

  // workspace: xemb [1024][256][64] bf16 + 64-short zero pad, hs
  unsigned short* xemb = (unsigned short*)d_ws;
  unsigned short* hs   = xemb + (size_t)S_*B_*E_ + 64;

  init_kernel<<<dim3((B_*S_)/(4*INIT_ROWS)), dim3(256), 0, stream>>>(
      x, init_W, init_b, init_g, init_be, xemb);

  mega_kernel<<<dim3(64), dim3(512), 0, stream>>>(
      xemb,
      enc_Wih, enc_Whh, enc_bih, enc_bhh,
      dec_Wih, dec_Whh, dec_bih, dec_bhh,
      eps,
      mu_W, mu_b, mu_g, mu_be,
      lv_W, lv_b, lv_g, lv_be,
      lh_W, lh_b, lh_g, lh_be,
      lc_W, lc_b, lc_g, lc_be,
      hs, out);

  out_kernel<<<dim3((B_*(S_-1))/16/4), dim3(256), 0, stream>>>(
      hs, act_W, act_b, time_W, time_b, out);
}

// Round 16
// 1112.871 us; speedup vs baseline: 1.1735x; 1.0196x over previous
//
#include <hip/hip_runtime.h>
#include <hip/hip_bf16.h>
#include <type_traits>

// LogVAE. R22 (from R21 @1134.7us best; mega ~957 = enc 476 + lat 5 + dec 476).
//  Final instruction shavings on the barrier-locked step loop:
//  (1) saddr-form hs store: uniform base hs + t*B*H (SGPR, SALU-incremented)
//      + loop-invariant per-lane element offset -> kills 2 v_adds/step (dec).
//  (2) xwin clamp removed: max unclamped row = 1031 -> ~34MB offset, inside
//      the xemb+hs workspace; garbage rows only feed gx for steps >= T that
//      are never consumed (traced for enc nwin=256 / dec nwin=255 + tail).
//  Everything else = R21 (2-window role ping-pong, 2+2+2+2 gx spread,
//  lgkmcnt-only barrier, R13 lane-rotated reg-dt core, fused latent).
//  PRE-COMMIT: if total gain < 8us, declare structural-latency ceiling next
//  round (ledger: R15 occupancy x, R16/R17 in-loop fusion x, splits
//  impossible — full h-dependence forces 1 barrier/step and 64 WGs).

#define B_ 256
#define S_ 1024
#define NF_ 32
#define E_ 64
#define H_ 128
#define L_ 64
#define C_ 31

#define ACTS_OFF 0
#define TS_OFF   8118528   // 256*1023*31
#define MU_OFF   8380416   // + 256*1023
#define LV_OFF   8396800   // + 256*64

#define LOG2E  1.44269504f
#define LOG2E2 2.88539008f

typedef __attribute__((ext_vector_type(8))) short short8;
typedef __attribute__((ext_vector_type(4))) float float4v;

__device__ inline unsigned short f2bf(float x){
  union { float f; unsigned u; } a; a.f = x;
  unsigned r = a.u + 0x7FFFu + ((a.u >> 16) & 1u);
  return (unsigned short)(r >> 16);
}
__device__ inline float frcp(float x){
#if __has_builtin(__builtin_amdgcn_rcpf)
  return __builtin_amdgcn_rcpf(x);
#else
  return 1.0f / x;
#endif
}
__device__ inline float fexp2(float x){
#if __has_builtin(__builtin_amdgcn_exp2f)
  return __builtin_amdgcn_exp2f(x);
#else
  return exp2f(x);
#endif
}
__device__ inline float fsig(float x){ return frcp(1.0f + fexp2(-LOG2E*x)); }
__device__ inline float leaky(float x){ return x >= 0.0f ? x : 0.01f*x; }
__device__ inline float wredsum(float v){
  v += __shfl_xor(v, 32, 64);
  v += __shfl_xor(v, 16, 64);
  v += __shfl_xor(v,  8, 64);
  v += __shfl_xor(v,  4, 64);
  v += __shfl_xor(v,  2, 64);
  v += __shfl_xor(v,  1, 64);
  return v;
}

// ---------------- Kernel A: x_emb = LN(leaky(x @ W.T + b)) -> bf16 [S][B][E] --
#define INIT_ROWS 16
__global__ __launch_bounds__(256) void init_kernel(
    const float* __restrict__ x, const float* __restrict__ W,
    const float* __restrict__ bias, const float* __restrict__ gam,
    const float* __restrict__ beta, unsigned short* __restrict__ xemb)
{
  if (blockIdx.x == 0 && threadIdx.x < 64)
    xemb[(size_t)S_*B_*E_ + threadIdx.x] = 0;

  const int wave = threadIdx.x >> 6, lane = threadIdx.x & 63;
  float wf[NF_];
  {
    const float4* wr = (const float4*)(W + lane * NF_);
    #pragma unroll
    for (int j = 0; j < NF_/4; ++j){
      float4 t = wr[j];
      wf[4*j+0] = t.x; wf[4*j+1] = t.y; wf[4*j+2] = t.z; wf[4*j+3] = t.w;
    }
  }
  const float bb = bias[lane], gg = gam[lane], be = beta[lane];

  const int r0 = (blockIdx.x * 4 + wave) * INIT_ROWS;
  for (int rr = 0; rr < INIT_ROWS; ++rr){
    const int ru = __builtin_amdgcn_readfirstlane(r0 + rr);  // wave-uniform row
    const int b = ru >> 10, s = ru & 1023;
    const float* xr = x + (size_t)ru * NF_;   // SGPR-based -> s_loads
    float acc = bb;
    #pragma unroll
    for (int k = 0; k < NF_; ++k)
      acc = fmaf(xr[k], wf[k], acc);
    acc = leaky(acc);
    float m = wredsum(acc) * (1.0f/64.0f);
    float d = acc - m;
    float v = wredsum(d*d) * (1.0f/64.0f);
    float y = d * rsqrtf(v + 1e-5f) * gg + be;
    xemb[((size_t)s * B_ + b) * E_ + lane] = f2bf(y);   // [S][B][E]
  }
}

// ---------------- Megakernel: enc lstm -> latent -> dec lstm -----------------
// grid=64 (4 batch/WG), block=512 (8 waves). lstm core = R13 structure.
__global__ __launch_bounds__(512, 2) void mega_kernel(
    const unsigned short* __restrict__ xemb,  // [S][256][64] bf16 (+64 pad)
    const float* __restrict__ encWih, const float* __restrict__ encWhh,
    const float* __restrict__ encbih, const float* __restrict__ encbhh,
    const float* __restrict__ decWih, const float* __restrict__ decWhh,
    const float* __restrict__ decbih, const float* __restrict__ decbhh,
    const float* __restrict__ eps,
    const float* __restrict__ mu_W, const float* __restrict__ mu_b,
    const float* __restrict__ mu_g, const float* __restrict__ mu_be,
    const float* __restrict__ lv_W, const float* __restrict__ lv_b,
    const float* __restrict__ lv_g, const float* __restrict__ lv_be,
    const float* __restrict__ lh_W, const float* __restrict__ lh_b,
    const float* __restrict__ lh_g, const float* __restrict__ lh_be,
    const float* __restrict__ lc_W, const float* __restrict__ lc_b,
    const float* __restrict__ lc_g, const float* __restrict__ lc_be,
    unsigned short* __restrict__ hs,          // [S-1][256][128] bf16
    float* __restrict__ out)
{
  __shared__ unsigned short hbuf[2][16*136];  // recurrence ping-pong (+8 pad/row)
  __shared__ float shT[4][H_];                // enc hT (f32)
  __shared__ float sml[4][2*L_];              // mu|lv per batch
  __shared__ float slat[4][L_];
  __shared__ float sdh[4][H_], sdc[4][H_];
  __shared__ float partA[8];

  const int tid = threadIdx.x;
  const int wave = tid >> 6, lane = tid & 63;
  const int q = lane >> 4, c16 = lane & 15;
  const int bt0 = blockIdx.x * 4;
  const int hu = wave * 16 + c16;
  unsigned short* hflat = &hbuf[0][0];
  const float4v z4 = (float4v){0.0f, 0.0f, 0.0f, 0.0f};
  float zero_f = 0.0f;

  for (int idx = tid; idx < 2*16*136; idx += 512) hflat[idx] = 0;
  __syncthreads();

  // x window machinery (shared by both phases). Lane A-row = c16 = 4*b + dt.
  const int xb = c16 >> 2, xdt = c16 & 3;
  const unsigned short* xbase = xemb + ((size_t)(bt0 + xb))*E_ + q*8;
  const size_t xrow = (size_t)B_*E_;

  using I0 = std::integral_constant<int,0>;
  using I1 = std::integral_constant<int,1>;
  using I2 = std::integral_constant<int,2>;
  using I3 = std::integral_constant<int,3>;
  auto nop = []{};

  // ================= LSTM runner (enc: DEC=false / dec: DEC=true) ==========
  auto run = [&](const float* Wih, const float* Whh, const float* bih,
                 const float* bhh, int T, auto decc){
    constexpr bool DEC = decltype(decc)::value;

    // Persistent B frags: kb 0..3 = Whh (K=0..128), kb 4..5 = Wih (K=128..192)
    short8 Bf[4][6];
    float bias[4];
    #pragma unroll
    for (int g = 0; g < 4; ++g){
      const int gcol = g*128 + hu;
      bias[g] = bih[gcol] + bhh[gcol];
      #pragma unroll
      for (int kb = 0; kb < 6; ++kb){
        union { short8 v; unsigned short u[8]; } tmp;
        #pragma unroll
        for (int j = 0; j < 8; ++j){
          int k = kb*32 + q*8 + j;
          float wv = (kb < 4) ? Whh[gcol*H_ + k] : Wih[gcol*E_ + (k - H_)];
          tmp.u[j] = f2bf(wv);
        }
        Bf[g][kb] = tmp.v;
      }
    }

    // h0/c0: buf0 rows {0,4,8,12} (other rows stay zero from initial memset)
    {
      int b = tid >> 7, k = tid & 127;   // 512 = 4*128
      hbuf[0][(4*b)*136 + k] = DEC ? f2bf(sdh[b][k]) : (unsigned short)0x3F80;
    }
    float cst = DEC ? sdc[q][hu] : 0.0f;
    __syncthreads();

    // No clamp (R22): max row read = 1031; offset ~34MB lands inside the
    // xemb+hs workspace; garbage rows only feed gx for steps >= T that are
    // never consumed (traced for enc nwin=256 / dec nwin=255 + tail).
    auto xwin = [&](int wt)->const unsigned short*{
      return xbase + (size_t)(wt + xdt) * xrow;
    };

    // Prologue: gxA = gx(0..3); nx = x(4..7) in flight.
    float4v gxA[4], gxB[4];
    short8 nx0, nx1, nxN0, nxN1;
    { const unsigned short* p = xwin(0);
      nx0 = *(const short8*)p; nx1 = *(const short8*)(p + 32); }
    #pragma unroll
    for (int g = 0; g < 4; ++g){
      float4v t = (float4v){bias[g], bias[g], bias[g], bias[g]};
      t = __builtin_amdgcn_mfma_f32_16x16x32_bf16(nx0, Bf[g][4], t, 0, 0, 0);
      gxA[g] = __builtin_amdgcn_mfma_f32_16x16x32_bf16(nx1, Bf[g][5], t, 0, 0, 0);
    }
    { const unsigned short* p = xwin(4);
      nx0 = *(const short8*)p; nx1 = *(const short8*)(p + 32); }
    nxN0 = nx0; nxN1 = nx1;   // defined-init; overwritten by window 0's dt1

    short8 Af0 = 0, Af1 = 0, Af2 = 0, Af3 = 0;

    const unsigned short* haR0 = hflat + (c16 & ~3)*136 + q*8;  // buf0
    const unsigned short* haR1 = haR0 + 2176;                   // buf1
    unsigned short* hw0 = hflat + (4*q)*136 + hu;               // write buf0
    unsigned short* hw1 = hw0 + 2176;                           // write buf1
    const unsigned hsoff = (unsigned)((bt0 + q)*H_ + hu);       // lane-invariant elt idx
    float h_last = 0.0f;                                        // enc hT capture

    // step: R13 core. hs store = saddr form (uniform base, SALU-stepped).
    auto step = [&](int t, auto dtc, float4v (&gxP)[4], auto&& pre){
      constexpr int dt = decltype(dtc)::value;
      const unsigned short* ha = (t & 1) ? haR1 : haR0;
      if ((c16 & 3) == dt){            // this step's h-supplier lanes
        Af0 = *(const short8*)(ha);
        Af1 = *(const short8*)(ha + 32);
        Af2 = *(const short8*)(ha + 64);
        Af3 = *(const short8*)(ha + 96);
      }
      pre();

      // K-split chains: aA = gx + kb0 + kb1 ; aB = kb2 + kb3 (from zero).
      float4v aA[4], aB[4];
      #pragma unroll
      for (int g = 0; g < 4; ++g)
        aA[g] = __builtin_amdgcn_mfma_f32_16x16x32_bf16(Af0, Bf[g][0], gxP[g], 0, 0, 0);
      #pragma unroll
      for (int g = 0; g < 4; ++g)
        aB[g] = __builtin_amdgcn_mfma_f32_16x16x32_bf16(Af2, Bf[g][2], z4, 0, 0, 0);
      #pragma unroll
      for (int g = 0; g < 4; ++g)
        aA[g] = __builtin_amdgcn_mfma_f32_16x16x32_bf16(Af1, Bf[g][1], aA[g], 0, 0, 0);
      #pragma unroll
      for (int g = 0; g < 4; ++g)
        aB[g] = __builtin_amdgcn_mfma_f32_16x16x32_bf16(Af3, Bf[g][3], aB[g], 0, 0, 0);

      float gi = aA[0][dt] + aB[0][dt];
      float gf = aA[1][dt] + aB[1][dt];
      float gg = aA[2][dt] + aB[2][dt];
      float go = aA[3][dt] + aB[3][dt];
      float ei  = fexp2(gi * LOG2E);
      float e2g = fexp2(gg * LOG2E2);
      float t1  = (ei * (e2g - 1.0f)) * frcp((1.0f + ei) * (1.0f + e2g));
      float sf  = fsig(gf);
      float c   = fmaf(sf, cst, t1);
      cst = c;
      float eo  = fexp2(go * LOG2E);
      float e2c = fexp2(fminf(c * LOG2E2, 126.0f));
      float h   = (eo * (e2c - 1.0f)) * frcp((1.0f + eo) * (1.0f + e2c));
      unsigned vv;
      asm("v_cvt_pk_bf16_f32 %0, %1, %2" : "=v"(vv) : "v"(h), "v"(zero_f));
      unsigned short hb16 = (unsigned short)vv;
      unsigned short* hw = (t & 1) ? hw0 : hw1;
      hw[0] = hb16;
      if (DEC){   // saddr store: base uniform in t, offset loop-invariant
        unsigned short* hst = hs + (size_t)t * (size_t)(B_*H_);
        hst[hsoff] = hb16;
      } else h_last = h;
      // Raw barrier: drain LDS only; globals stay in flight (R7). Pre-
      // lgkmcnt sched_barrier removed (R19): "memory" clobber orders the
      // ds_write; VALU may sink into the write-drain shadow.
      asm volatile("s_waitcnt lgkmcnt(0)" ::: "memory");
      __builtin_amdgcn_s_barrier();
      __builtin_amdgcn_sched_barrier(0);   // KEEP: no IR fence on s_barrier
    };

    // window: 4 steps consuming gxCur; builds gxNxt (2 MFMAs per dt slot)
    // from nxc (= x(t0+4..t0+7)); loads x(t0+8..t0+11) into nxn at dt1.
    // Role ping-pong across windows: zero rotation movs (R21).
    auto window = [&](int t0, float4v (&gxCur)[4], float4v (&gxNxt)[4],
                      short8& nxc0, short8& nxc1, short8& nxn0, short8& nxn1){
      step(t0+0, I0{}, gxCur, [&]{
        float4v tt = (float4v){bias[0], bias[0], bias[0], bias[0]};
        tt = __builtin_amdgcn_mfma_f32_16x16x32_bf16(nxc0, Bf[0][4], tt, 0, 0, 0);
        gxNxt[0] = __builtin_amdgcn_mfma_f32_16x16x32_bf16(nxc1, Bf[0][5], tt, 0, 0, 0);
      });
      step(t0+1, I1{}, gxCur, [&]{
        const unsigned short* p = xwin(t0 + 8);
        nxn0 = *(const short8*)p; nxn1 = *(const short8*)(p + 32);
        float4v tt = (float4v){bias[1], bias[1], bias[1], bias[1]};
        tt = __builtin_amdgcn_mfma_f32_16x16x32_bf16(nxc0, Bf[1][4], tt, 0, 0, 0);
        gxNxt[1] = __builtin_amdgcn_mfma_f32_16x16x32_bf16(nxc1, Bf[1][5], tt, 0, 0, 0);
      });
      step(t0+2, I2{}, gxCur, [&]{
        float4v tt = (float4v){bias[2], bias[2], bias[2], bias[2]};
        tt = __builtin_amdgcn_mfma_f32_16x16x32_bf16(nxc0, Bf[2][4], tt, 0, 0, 0);
        gxNxt[2] = __builtin_amdgcn_mfma_f32_16x16x32_bf16(nxc1, Bf[2][5], tt, 0, 0, 0);
      });
      step(t0+3, I3{}, gxCur, [&]{
        float4v tt = (float4v){bias[3], bias[3], bias[3], bias[3]};
        tt = __builtin_amdgcn_mfma_f32_16x16x32_bf16(nxc0, Bf[3][4], tt, 0, 0, 0);
        gxNxt[3] = __builtin_amdgcn_mfma_f32_16x16x32_bf16(nxc1, Bf[3][5], tt, 0, 0, 0);
      });
    };

    const int nwin = T >> 2, ntail = T & 3;
    int w = 0;
    for (; w + 2 <= nwin; w += 2){
      window((w    ) << 2, gxA, gxB, nx0,  nx1,  nxN0, nxN1);
      window((w + 1) << 2, gxB, gxA, nxN0, nxN1, nx0,  nx1);
    }
    if (w < nwin){   // odd nwin (dec: 255): unpaired window; tail reads gxB
      window(w << 2, gxA, gxB, nx0, nx1, nxN0, nxN1);
      if (ntail > 0) step(nwin*4+0, I0{}, gxB, nop);
      if (ntail > 1) step(nwin*4+1, I1{}, gxB, nop);
      if (ntail > 2) step(nwin*4+2, I2{}, gxB, nop);
    } else {         // even nwin (enc: 256): tail reads gxA
      if (ntail > 0) step(nwin*4+0, I0{}, gxA, nop);
      if (ntail > 1) step(nwin*4+1, I1{}, gxA, nop);
      if (ntail > 2) step(nwin*4+2, I2{}, gxA, nop);
    }

    if (!DEC){ shT[q][hu] = h_last; __syncthreads(); }  // hT for latent
  };

  // ======================= ENCODER =======================
  run(encWih, encWhh, encbih, encbhh, S_, std::integral_constant<bool,false>{});

  // ======================= LATENT (in-WG, 4 batches) =====
  {
    const int bb = tid >> 7, slot = tid & 127;
    const int unit = slot & 63;
    const bool isLv = slot >= 64;
    // mu/lv: per-wave LN over 64 units (wave == (bb,isLv) group exactly)
    const float* W = isLv ? lv_W : mu_W;
    float a = (isLv ? lv_b : mu_b)[unit];
    const float4* wr = (const float4*)(W + unit*H_);
    #pragma unroll 4
    for (int j = 0; j < H_/4; ++j){
      float4 w4 = wr[j];
      a += w4.x*shT[bb][4*j] + w4.y*shT[bb][4*j+1]
         + w4.z*shT[bb][4*j+2] + w4.w*shT[bb][4*j+3];
    }
    a = leaky(a);
    float m = wredsum(a) * (1.0f/L_);
    float d = a - m;
    float v = wredsum(d*d) * (1.0f/L_);
    float y = d * rsqrtf(v + 1e-5f) * (isLv ? lv_g : mu_g)[unit]
            + (isLv ? lv_be : mu_be)[unit];
    out[(isLv ? LV_OFF : MU_OFF) + (size_t)(bt0 + bb)*L_ + unit] = y;
    sml[bb][slot] = y;
    __syncthreads();
    if (!isLv)
      slat[bb][unit] = sml[bb][unit]
                     + eps[(size_t)(bt0 + bb)*L_ + unit] * expf(0.5f*sml[bb][64 + unit]);
    __syncthreads();
    // dh0/dc0: LN over 128 units (waves 2bb / 2bb+1)
    #pragma unroll 1
    for (int which = 0; which < 2; ++which){
      const float* W2 = which ? lc_W : lh_W;
      float p = (which ? lc_b : lh_b)[slot];
      const float4* w2 = (const float4*)(W2 + slot*L_);
      #pragma unroll 4
      for (int j = 0; j < L_/4; ++j){
        float4 w4 = w2[j];
        p += w4.x*slat[bb][4*j] + w4.y*slat[bb][4*j+1]
           + w4.z*slat[bb][4*j+2] + w4.w*slat[bb][4*j+3];
      }
      p = leaky(p);
      float s = wredsum(p);
      if (lane == 0) partA[wave] = s;
      __syncthreads();
      float mean = (partA[2*bb] + partA[2*bb+1]) * (1.0f/H_);
      __syncthreads();
      float dd = p - mean;
      float s2 = wredsum(dd*dd);
      if (lane == 0) partA[wave] = s2;
      __syncthreads();
      float var = (partA[2*bb] + partA[2*bb+1]) * (1.0f/H_);
      __syncthreads();
      float yy = dd * rsqrtf(var + 1e-5f) * (which ? lc_g : lh_g)[slot]
               + (which ? lc_be : lh_be)[slot];
      (which ? sdc : sdh)[bb][slot] = yy;
    }
  }
  __syncthreads();

  // ======================= DECODER (hs stores, free) =====
  run(decWih, decWhh, decbih, decbhh, S_-1, std::integral_constant<bool,true>{});
}

// ---------------- Kernel D: acts/ts heads via MFMA (N=32: 31 acts + ts) -----
__global__ __launch_bounds__(256) void out_kernel(
    const unsigned short* __restrict__ hs,   // [1023][256][128] bf16
    const float* __restrict__ actW, const float* __restrict__ actB,
    const float* __restrict__ timeW, const float* __restrict__ timeB,
    float* __restrict__ out)
{
  const int wave = threadIdx.x >> 6, lane = threadIdx.x & 63;
  const int quad = lane >> 4, c16 = lane & 15;
  const int mt = blockIdx.x * 4 + wave;      // M-tile of 16 rows (r = t*256 + b)
  short8 Wf[2][4]; float biasn[2];
  #pragma unroll
  for (int ti = 0; ti < 2; ++ti){
    const int n = ti*16 + c16;
    biasn[ti] = (n < C_) ? actB[n] : timeB[0];
    #pragma unroll
    for (int kb = 0; kb < 4; ++kb){
      union { short8 v; unsigned short u[8]; } tmp;
      #pragma unroll
      for (int j = 0; j < 8; ++j){
        int k = kb*32 + quad*8 + j;
        tmp.u[j] = f2bf((n < C_) ? actW[n*H_ + k] : timeW[k]);
      }
      Wf[ti][kb] = tmp.v;
    }
  }
  const unsigned short* hp = hs + ((size_t)mt*16 + c16)*H_ + quad*8;
  float4v acc[2];
  #pragma unroll
  for (int ti = 0; ti < 2; ++ti) acc[ti] = (float4v){biasn[ti], biasn[ti], biasn[ti], biasn[ti]};
  #pragma unroll
  for (int kb = 0; kb < 4; ++kb){
    short8 a = *(const short8*)(hp + kb*32);
    acc[0] = __builtin_amdgcn_mfma_f32_16x16x32_bf16(a, Wf[0][kb], acc[0], 0, 0, 0);
    acc[1] = __builtin_amdgcn_mfma_f32_16x16x32_bf16(a, Wf[1][kb], acc[1], 0, 0, 0);
  }
  #pragma unroll
  for (int ti = 0; ti < 2; ++ti){
    const int n = ti*16 + c16;
    #pragma unroll
    for (int r = 0; r < 4; ++r){
      int rr = mt*16 + quad*4 + r;
      int tt = rr >> 8, b = rr & 255;
      float v = acc[ti][r];
      if (n < C_) out[ACTS_OFF + ((size_t)b*1023 + tt)*C_ + n] = v;
      else        out[TS_OFF + (size_t)b*1023 + tt] = v;
    }
  }
}

// ---------------- launch ----------------------------------------------------
extern "C" void kernel_launch(void* const* d_in, const int* in_sizes, int n_in,
                              void* d_out, int out_size, void* d_ws, size_t ws_size,
                              hipStream_t stream)
{
  (void)in_sizes; (void)n_in; (void)out_size; (void)ws_size;
  const float* x       = (const float*)d_in[0];
  const float* eps     = (const float*)d_in[1];
  const float* init_W  = (const float*)d_in[2];
  const float* init_b  = (const float*)d_in[3];
  const float* init_g  = (const float*)d_in[4];
  const float* init_be = (const float*)d_in[5];
  const float* enc_Wih = (const float*)d_in[6];
  const float* enc_Whh = (const float*)d_in[7];
  const float* enc_bih = (const float*)d_in[8];
  const float* enc_bhh = (const float*)d_in[9];
  const float* mu_W  = (const float*)d_in[10];
  const float* mu_b  = (const float*)d_in[11];
  const float* mu_g  = (const float*)d_in[12];
  const float* mu_be = (const float*)d_in[13];
  const float* lv_W  = (const float*)d_in[14];
  const float* lv_b  = (const float*)d_in[15];
  const float* lv_g  = (const float*)d_in[16];
  const float* lv_be = (const float*)d_in[17];
  const float* dec_Wih = (const float*)d_in[18];
  const float* dec_Whh = (const float*)d_in[19];
  const float* dec_bih = (const float*)d_in[20];
  const float* dec_bhh = (const float*)d_in[21];
  const float* lh_W  = (const float*)d_in[22];
  const float* lh_b  = (const float*)d_in[23];
  const float* lh_g  = (const float*)d_in[24];
  const float* lh_be = (const float*)d_in[25];
  const float* lc_W  = (const float*)d_in[26];
  const float* lc_b  = (const float*)d_in[27];
  const float* lc_g  = (const float*)d_in[28];
  const float* lc_be = (const float*)d_in[29];
  const float* act_W  = (const float*)d_in[30];
  const float* act_b  = (const float*)d_in[31];
  const float* time_W = (const float*)d_in[32];
  const float* time_b = (const float*)d_in[33];
  float* out = (float*)d_out;

  // workspace: xemb [1024][256][64] bf16 + 64-short zero pad, hs
  unsigned short* xemb = (unsigned short*)d_ws;
  unsigned short* hs   = xemb + (size_t)S_*B_*E_ + 64;

  init_kernel<<<dim3((B_*S_)/(4*INIT_ROWS)), dim3(256), 0, stream>>>(
      x, init_W, init_b, init_g, init_be, xemb);

  mega_kernel<<<dim3(64), dim3(512), 0, stream>>>(
      xemb,
      enc_Wih, enc_Whh, enc_bih, enc_bhh,
      dec_Wih, dec_Whh, dec_bih, dec_bhh,
      eps,
      mu_W, mu_b, mu_g, mu_be,
      lv_W, lv_b, lv_g, lv_be,
      lh_W, lh_b, lh_g, lh_be,
      lc_W, lc_b, lc_g, lc_be,
      hs, out);

  out_kernel<<<dim3((B_*(S_-1))/16/4), dim3(256), 0, stream>>>(
      hs, act_W, act_b, time_W, time_b, out);
}